// Round 9
// baseline (6719.429 us; speedup 1.0000x reference)
//
#include <hip/hip_runtime.h>
#include <math.h>

#define NIMG 64
#define NCAP 64
#define NREG 36      // S: image regions
#define NWORD 20     // Q: caption words
#define EMBED 1024   // D
#define SIMDIM 256   // SIM
#define H1 512       // rcr matrix-MLP hidden
#define HSD 128      // rcr smooth-MLP hidden
#define EPS 1e-8f

// padded LDS row strides (u16 units)
#define QSTR 1032
#define SMSTR 264
#define PSTR 72
#define ATSTR 37

typedef unsigned short u16t;
typedef __bf16 bf8 __attribute__((ext_vector_type(8)));
typedef short  s8i __attribute__((ext_vector_type(8)));
typedef float  f4  __attribute__((ext_vector_type(4)));

__device__ __forceinline__ float wsum(float v) {
#pragma unroll
  for (int o = 32; o > 0; o >>= 1) v += __shfl_xor(v, o);
  return v;
}
__device__ __forceinline__ float wmax(float v) {
#pragma unroll
  for (int o = 32; o > 0; o >>= 1) v = fmaxf(v, __shfl_xor(v, o));
  return v;
}
__device__ __forceinline__ float ftanh(float x) {
  x = fminf(fmaxf(x, -15.f), 15.f);
  float e = __expf(2.f * x);
  return (e - 1.f) / (e + 1.f);
}
__device__ __forceinline__ float d4(float4 a, float4 b) {
  return a.x*b.x + a.y*b.y + a.z*b.z + a.w*b.w;
}
__device__ __forceinline__ u16t f2bf(float f) {
  unsigned u = __float_as_uint(f);
  u += 0x7FFFu + ((u >> 16) & 1u);
  return (u16t)(u >> 16);
}
__device__ __forceinline__ float bf2f(u16t h) { return __uint_as_float(((unsigned)h) << 16); }
__device__ __forceinline__ bf8 zero8() {
  s8i z = {0,0,0,0,0,0,0,0};
  return __builtin_bit_cast(bf8, z);
}
#define MFMA16(a, b, c) __builtin_amdgcn_mfma_f32_16x16x32_bf16((a), (b), (c), 0, 0, 0)

// d_ws layout (u16 elements) for weights
#define WS_ALV   0u
#define WS_KW    786432u
#define WS_MW1   983040u
#define WS_MW2   1245184u
#define WS_SW1   2293760u
#define WS_IMG   2359296u
#define WS_CTXT  4718592u
#define WS_END   8912896u
#define N_CVT    4718592u

// byte offsets of inter-kernel state (after weights)
#define OFFB_MAT    17825792ull                 // int8 [4096][20][1024] = 83886080
#define OFFB_SMID   (OFFB_MAT + 83886080ull)    // u16  [4096][20][256] = 41943040
#define OFFB_SHIG   (OFFB_SMID + 41943040ull)   // f32  [4096][256]     = 4194304
#define OFFB_SMOOTH (OFFB_SHIG + 4194304ull)    // f32  [4096][20]      = 327680
#define WS_FULL_BYTES (OFFB_SMOOTH + 327680ull) // ~148.2 MB

// ---------------- pre-pass 1: weights + img -> bf16 ----------------
__global__ void cvt_kernel(const float* __restrict__ alv, const float* __restrict__ kw,
                           const float* __restrict__ mw1, const float* __restrict__ mw2,
                           const float* __restrict__ sw1, const float* __restrict__ img,
                           u16t* __restrict__ ws) {
  for (unsigned i = blockIdx.x * blockDim.x + threadIdx.x; i < N_CVT; i += gridDim.x * blockDim.x) {
    unsigned o = i; float v;
    if (o < 786432u) v = alv[o];
    else if ((o -= 786432u) < 196608u) v = kw[o];
    else if ((o -= 196608u) < 262144u) v = mw1[o];
    else if ((o -= 262144u) < 1048576u) v = mw2[o];
    else if ((o -= 1048576u) < 65536u) v = sw1[o];
    else { o -= 65536u; v = img[o]; }
    ws[i] = f2bf(v);
  }
}

// ---------------- pre-pass 2: ctxT[img][d][s(pad 64)] bf16 ----------------
__global__ void ctxt_kernel(const float* __restrict__ img, u16t* __restrict__ ctxT) {
  __shared__ float tile[36 * 65];
  int b = blockIdx.x;
  int im = b >> 4, dt = (b & 15) * 64;
  const float* src = img + (size_t)im * 36 * 1024 + dt;
  for (int e = threadIdx.x; e < 36 * 64; e += 256) {
    int s = e >> 6, dd = e & 63;
    tile[s * 65 + dd] = src[s * 1024 + dd];
  }
  __syncthreads();
  u16t* dst = ctxT + (size_t)im * 65536 + dt * 64;
  for (int o = threadIdx.x; o < 4096; o += 256) {
    int dd = o >> 6, sp = o & 63;
    dst[dd * 64 + sp] = (sp < 36) ? f2bf(tile[sp * 65 + dd]) : (u16t)0;
  }
}

// =================== K1: attention + F + regulators (per 2 pairs) ===================
// 1024 threads / 16 waves, ~121KB LDS, 1 block/CU. Runs once per m-step.
__global__ __launch_bounds__(1024, 4) void simenc_k1(
    const float* __restrict__ cap_emb,
    const float* __restrict__ alv_b,
    const float* __restrict__ rar_qw, const float* __restrict__ rar_qb,
    const float* __restrict__ rar_kb,
    const float* __restrict__ rar_vw, const float* __restrict__ rar_vb,
    const float* __restrict__ sb1, const float* __restrict__ sw2, const float* __restrict__ sb2,
    const float* __restrict__ eval_w, const float* __restrict__ eval_b,
    const u16t* __restrict__ ws,
    signed char* __restrict__ mat_g, u16t* __restrict__ smid_g,
    float* __restrict__ shig_g, float* __restrict__ smooth_g,
    int m, float* __restrict__ out)
{
  __shared__ __attribute__((aligned(16))) u16t qsrep[2][NWORD * QSTR];   // 82560B
  __shared__ __attribute__((aligned(16))) u16t smidb[2][NWORD * SMSTR];  // 21120B
  __shared__ __attribute__((aligned(16))) u16t p_bf[2][NWORD * PSTR];    //  5760B
  __shared__ float attnT[2][NWORD * ATSTR];                              //  5920B
  __shared__ float colscale[2][36];
  __shared__ float smoothq[2][NWORD];
  __shared__ float sim_hig[2][SIMDIM];
  __shared__ float red[2][16 * NWORD];
  __shared__ float rq[2][NWORD];
  __shared__ float logits[2][NWORD];
  __shared__ float wsm[2][NWORD];
  __shared__ float ssig_s[2];

  const int tid = threadIdx.x;
  const int lane = tid & 63;
  const int wv = tid >> 6;      // 0..15
  const int lr = lane & 15;
  const int lg = lane >> 4;
  const int koff = lg * 8;

  // XCD-aware swizzle
  const int xcd = blockIdx.x & 7;
  const int j_  = blockIdx.x >> 3;
  const int img  = xcd * 8 + (j_ & 7);
  const int cap0 = (j_ >> 3) * 2;
  const int pid0 = img * NCAP + cap0;

  const float* qryp[2];
  qryp[0] = cap_emb + (size_t)cap0 * (NWORD * EMBED);
  qryp[1] = cap_emb + (size_t)(cap0 + 1) * (NWORD * EMBED);
  const u16t* imgW  = ws + WS_IMG + (size_t)img * (NREG * EMBED);
  const u16t* ctxTW = ws + WS_CTXT + (size_t)img * (EMBED * 64);
  const u16t* alvW = ws + WS_ALV + (size_t)m * (SIMDIM * EMBED);
  const u16t* kwW  = ws + WS_KW  + (size_t)m * (SIMDIM * SIMDIM);
  const u16t* sw1W = ws + WS_SW1 + (size_t)m * (HSD * SIMDIM);

  // ---- init: smooth + sim_hig state ----
  if (tid < 40) {
    int p = tid / 20, q = tid % 20;
    smoothq[p][q] = (m == 0) ? 9.0f : smooth_g[(size_t)(pid0 + p) * 20 + q];
  }
  if (m > 0 && tid < 512) {
    int p = tid >> 8, t = tid & 255;
    sim_hig[p][t] = shig_g[(size_t)(pid0 + p) * 256 + t];
  }
  __syncthreads();

  // ---- A: qm = qry * matrix -> qsrep (bf16); thread owns col d=tid ----
#pragma unroll
  for (int p = 0; p < 2; ++p) {
    const float* qr = qryp[p];
    if (m == 0) {
#pragma unroll 4
      for (int q = 0; q < NWORD; ++q)
        qsrep[p][q * QSTR + tid] = f2bf(qr[q * 1024 + tid]);
    } else {
      const signed char* mg = mat_g + (size_t)(pid0 + p) * 20480;
#pragma unroll 4
      for (int q = 0; q < NWORD; ++q) {
        float mv = (float)mg[q * 1024 + tid] * (1.f / 127.f);
        qsrep[p][q * QSTR + tid] = f2bf(qr[q * 1024 + tid] * mv);
      }
    }
  }
  __syncthreads();

  // ---- B: attnT = leaky(qm . ctx) via MFMA (waves 0..11) ----
  if (wv < 12) {
    int p = wv / 6, sub = wv % 6;
    int q0 = (sub & 1) * 16, s0 = (sub >> 1) * 16;
    int ari = q0 + lr; bool am = ari >= NWORD; int ar = am ? 0 : ari;
    int bri = s0 + lr; bool bm = bri >= NREG;  int br = bm ? 0 : bri;
    const u16t* ap = qsrep[p] + ar * QSTR + koff;
    const u16t* bp = imgW + (size_t)br * 1024 + koff;
    f4 acc0 = {0.f,0.f,0.f,0.f}, acc1 = {0.f,0.f,0.f,0.f};
#pragma unroll 2
    for (int kk = 0; kk < 32; kk += 2) {
      bf8 a0 = *(const bf8*)(ap + kk * 32);       if (am) a0 = zero8();
      bf8 b0 = *(const bf8*)(bp + kk * 32);       if (bm) b0 = zero8();
      bf8 a1 = *(const bf8*)(ap + (kk + 1) * 32); if (am) a1 = zero8();
      bf8 b1 = *(const bf8*)(bp + (kk + 1) * 32); if (bm) b1 = zero8();
      acc0 = MFMA16(a0, b0, acc0);
      acc1 = MFMA16(a1, b1, acc1);
    }
    f4 acc = acc0 + acc1;
#pragma unroll
    for (int r = 0; r < 4; ++r) {
      int q = q0 + lg * 4 + r, s = s0 + lr;
      if (q < NWORD && s < NREG) {
        float x = acc[r];
        attnT[p][q * ATSTR + s] = (x > 0.f) ? x : 0.1f * x;
      }
    }
  }
  __syncthreads();

  // ---- C: l2norm over q per s ----
  if (tid < 72) {
    int p = tid / 36, s = tid % 36;
    float ss = 0.f;
#pragma unroll
    for (int q = 0; q < NWORD; ++q) { float v = attnT[p][q * ATSTR + s]; ss += v * v; }
    colscale[p][s] = 1.f / (sqrtf(ss) + EPS);
  }
  __syncthreads();

  // ---- D: softmax over s per q ----
#pragma unroll
  for (int pass = 0; pass < 3; ++pass) {
    int task = wv + pass * 16;
    if (task < 40) {
      int p = task / 20, q = task % 20;
      float x = (lane < NREG)
              ? attnT[p][q * ATSTR + lane] * colscale[p][lane] * smoothq[p][q] : -1e30f;
      float mx = wmax(x);
      float e = (lane < NREG) ? __expf(x - mx) : 0.f;
      float s = wsum(e);
      p_bf[p][q * PSTR + lane] = f2bf(e / s);
    }
  }
  __syncthreads();

  // ---- E: wctx = p . ctx; pass1 wctx->LDS + norm partials; pass2 sim_rep ----
  {
    float s2[2][8];
#pragma unroll
    for (int p = 0; p < 2; ++p)
#pragma unroll
      for (int i = 0; i < 8; ++i) s2[p][i] = 0.f;
#pragma unroll
    for (int nt = 0; nt < 4; ++nt) {
      int d0 = wv * 64 + nt * 16;
      const u16t* bp = ctxTW + (size_t)(d0 + lr) * 64 + koff;
      bf8 b0 = *(const bf8*)(bp);
      bf8 b1 = *(const bf8*)(bp + 32);
      int d = d0 + lr;
#pragma unroll
      for (int p = 0; p < 2; ++p)
#pragma unroll
        for (int m2 = 0; m2 < 2; ++m2) {
          int row = m2 * 16 + lr;
          bf8 pa0, pa1;
          if (m2 == 0 || row < NWORD) {
            pa0 = *(const bf8*)(p_bf[p] + row * PSTR + koff);
            pa1 = *(const bf8*)(p_bf[p] + row * PSTR + 32 + koff);
          } else { pa0 = zero8(); pa1 = zero8(); }
          f4 acc = {0.f,0.f,0.f,0.f};
          acc = MFMA16(pa0, b0, acc);
          acc = MFMA16(pa1, b1, acc);
#pragma unroll
          for (int r = 0; r < 4; ++r) {
            int q = m2 * 16 + lg * 4 + r;
            s2[p][m2 * 4 + r] += acc[r] * acc[r];
            if (q < NWORD) qsrep[p][q * QSTR + d] = f2bf(acc[r]);
          }
        }
    }
#pragma unroll
    for (int o = 1; o < 16; o <<= 1)
#pragma unroll
      for (int p = 0; p < 2; ++p)
#pragma unroll
        for (int i = 0; i < 8; ++i) s2[p][i] += __shfl_xor(s2[p][i], o);
    if (lr == 0)
#pragma unroll
      for (int p = 0; p < 2; ++p) {
#pragma unroll
        for (int r = 0; r < 4; ++r) red[p][wv * 20 + lg * 4 + r] = s2[p][r];
        if (lg == 0)
#pragma unroll
          for (int r = 0; r < 4; ++r) red[p][wv * 20 + 16 + r] = s2[p][4 + r];
      }
    __syncthreads();
    if (tid < 40) {
      int p = tid / 20, q = tid % 20;
      float s = 0.f;
#pragma unroll
      for (int w = 0; w < 16; ++w) s += red[p][w * 20 + q];
      rq[p][q] = 1.f / (sqrtf(s) + EPS);
    }
    __syncthreads();
#pragma unroll
    for (int p = 0; p < 2; ++p) {
      const float* qr = qryp[p];
#pragma unroll
      for (int nt = 0; nt < 4; ++nt) {
        int d = wv * 64 + nt * 16 + lr;
#pragma unroll
        for (int m2 = 0; m2 < 2; ++m2)
#pragma unroll
          for (int r = 0; r < 4; ++r) {
            int q = m2 * 16 + lg * 4 + r;
            if (q < NWORD) {
              float wn = bf2f(qsrep[p][q * QSTR + d]) * rq[p][q];
              float t = qr[q * 1024 + d] - wn;
              qsrep[p][q * QSTR + d] = f2bf(t * t);
            }
          }
      }
    }
  }
  __syncthreads();

  // ---- F: sim_mid = l2norm(sim_rep . alv_w^T + b); writes smidb + smid_g ----
  {
    int t_ = wv * 16 + lr;
    const u16t* bp = alvW + (size_t)t_ * 1024 + koff;
    int ari = 16 + lr; bool am = ari >= NWORD; int ar = am ? 0 : ari;
    f4 a[2][2];
#pragma unroll
    for (int p = 0; p < 2; ++p) { a[p][0] = (f4){0,0,0,0}; a[p][1] = (f4){0,0,0,0}; }
#pragma unroll 2
    for (int kk = 0; kk < 32; ++kk) {
      bf8 b = *(const bf8*)(bp + kk * 32);
#pragma unroll
      for (int p = 0; p < 2; ++p) {
        bf8 x0 = *(const bf8*)(qsrep[p] + lr * QSTR + kk * 32 + koff);
        bf8 x1 = *(const bf8*)(qsrep[p] + ar * QSTR + kk * 32 + koff); if (am) x1 = zero8();
        a[p][0] = MFMA16(x0, b, a[p][0]);
        a[p][1] = MFMA16(x1, b, a[p][1]);
      }
    }
    float bias = alv_b[m * SIMDIM + t_];
    float s2[2][8];
#pragma unroll
    for (int p = 0; p < 2; ++p) {
#pragma unroll
      for (int r = 0; r < 4; ++r) { a[p][0][r] += bias; s2[p][r] = a[p][0][r] * a[p][0][r]; }
#pragma unroll
      for (int r = 0; r < 4; ++r) {
        a[p][1][r] += bias;
        s2[p][4 + r] = (lg == 0) ? a[p][1][r] * a[p][1][r] : 0.f;
      }
    }
#pragma unroll
    for (int o = 1; o < 16; o <<= 1)
#pragma unroll
      for (int p = 0; p < 2; ++p)
#pragma unroll
        for (int i = 0; i < 8; ++i) s2[p][i] += __shfl_xor(s2[p][i], o);
    if (lr == 0)
#pragma unroll
      for (int p = 0; p < 2; ++p) {
#pragma unroll
        for (int r = 0; r < 4; ++r) red[p][wv * 20 + lg * 4 + r] = s2[p][r];
        if (lg == 0)
#pragma unroll
          for (int r = 0; r < 4; ++r) red[p][wv * 20 + 16 + r] = s2[p][4 + r];
      }
    __syncthreads();
    if (tid < 40) {
      int p = tid / 20, q = tid % 20;
      float s = 0.f;
#pragma unroll
      for (int w = 0; w < 16; ++w) s += red[p][w * 20 + q];
      rq[p][q] = 1.f / (sqrtf(s) + EPS);
    }
    __syncthreads();
#pragma unroll
    for (int p = 0; p < 2; ++p) {
      u16t* sg = smid_g + (size_t)(pid0 + p) * 5120;
#pragma unroll
      for (int r = 0; r < 4; ++r) {
        int q = lg * 4 + r;
        float v = a[p][0][r] * rq[p][q];
        u16t hv = f2bf(v);
        ((float*)(qsrep[p] + q * QSTR + 512))[t_] = v;   // smid f32 overlay
        smidb[p][q * SMSTR + t_] = hv;
        sg[q * 256 + t_] = hv;
      }
      if (lg == 0)
#pragma unroll
        for (int r = 0; r < 4; ++r) {
          int q = 16 + r;
          float v = a[p][1][r] * rq[p][q];
          u16t hv = f2bf(v);
          ((float*)(qsrep[p] + q * QSTR + 512))[t_] = v;
          smidb[p][q * SMSTR + t_] = hv;
          sg[q * 256 + t_] = hv;
        }
    }
  }
  __syncthreads();

  // ---- G: sim_hig = mean_q sim_mid (m==0) ----
  if (m == 0 && tid < 512) {
    int p = tid >> 8, t = tid & 255;
    float s = 0.f;
#pragma unroll
    for (int q = 0; q < NWORD; ++q) s += ((const float*)(qsrep[p] + q * QSTR + 512))[t];
    sim_hig[p][t] = s * (1.f / NWORD);
  }
  __syncthreads();

  // ---- hs/ss: smooth update (m<2); waves 0..7 ----
  if (m < 2) {
    if (wv < 8) {
      int j0 = wv * 16;
      int ari = 16 + lr; bool am = ari >= NWORD; int ar = am ? 0 : ari;
      f4 h[2][2];
#pragma unroll
      for (int p = 0; p < 2; ++p) { h[p][0] = (f4){0,0,0,0}; h[p][1] = (f4){0,0,0,0}; }
#pragma unroll 2
      for (int kk = 0; kk < 8; ++kk) {
        bf8 b = *(const bf8*)(sw1W + (size_t)(j0 + lr) * 256 + kk * 32 + koff);
#pragma unroll
        for (int p = 0; p < 2; ++p) {
          bf8 x0 = *(const bf8*)(smidb[p] + lr * SMSTR + kk * 32 + koff);
          bf8 x1 = *(const bf8*)(smidb[p] + ar * SMSTR + kk * 32 + koff); if (am) x1 = zero8();
          h[p][0] = MFMA16(x0, b, h[p][0]);
          h[p][1] = MFMA16(x1, b, h[p][1]);
        }
      }
      int j = j0 + lr;
      float bias = sb1[m * HSD + j];
      float s2v = sw2[m * HSD + j];
      float part[2][8];
#pragma unroll
      for (int p = 0; p < 2; ++p) {
#pragma unroll
        for (int r = 0; r < 4; ++r) part[p][r] = ftanh(h[p][0][r] + bias) * s2v;
#pragma unroll
        for (int r = 0; r < 4; ++r)
          part[p][4 + r] = (lg == 0) ? ftanh(h[p][1][r] + bias) * s2v : 0.f;
      }
#pragma unroll
      for (int o = 1; o < 16; o <<= 1)
#pragma unroll
        for (int p = 0; p < 2; ++p)
#pragma unroll
          for (int i = 0; i < 8; ++i) part[p][i] += __shfl_xor(part[p][i], o);
      if (lr == 0)
#pragma unroll
        for (int p = 0; p < 2; ++p) {
#pragma unroll
          for (int r = 0; r < 4; ++r) red[p][wv * 20 + lg * 4 + r] = part[p][r];
          if (lg == 0)
#pragma unroll
            for (int r = 0; r < 4; ++r) red[p][wv * 20 + 16 + r] = part[p][4 + r];
        }
    }
    __syncthreads();
    if (tid < 40) {
      int p = tid / 20, q = tid % 20;
      float s = 0.f;
#pragma unroll
      for (int w = 0; w < 8; ++w) s += red[p][w * 20 + q];
      float ns = fmaxf(0.f, s + sb2[m] + smoothq[p][q]);
      smooth_g[(size_t)(pid0 + p) * 20 + q] = ns;
    }
    __syncthreads();
  }

  // ---- I: mid_k via MFMA + inline hqu, fused logit reduce ----
  {
    int t_ = wv * 16 + lr;
    int ari = 16 + lr; bool am = ari >= NWORD; int ar = am ? 0 : ari;
    float hq[2];
#pragma unroll
    for (int p = 0; p < 2; ++p) {
      const float4* wq = (const float4*)(rar_qw + ((size_t)m * SIMDIM + t_) * SIMDIM);
      const float4* sh = (const float4*)sim_hig[p];
      float hacc = 0.f;
#pragma unroll 2
      for (int i = 0; i < SIMDIM / 4; ++i) hacc += d4(wq[i], sh[i]);
      hq[p] = ftanh(hacc + rar_qb[m * SIMDIM + t_]) * rar_vw[m * SIMDIM + t_];
    }
    f4 k[2][2];
#pragma unroll
    for (int p = 0; p < 2; ++p) { k[p][0] = (f4){0,0,0,0}; k[p][1] = (f4){0,0,0,0}; }
#pragma unroll 2
    for (int kk = 0; kk < 8; ++kk) {
      bf8 b = *(const bf8*)(kwW + (size_t)t_ * 256 + kk * 32 + koff);
#pragma unroll
      for (int p = 0; p < 2; ++p) {
        bf8 x0 = *(const bf8*)(smidb[p] + lr * SMSTR + kk * 32 + koff);
        bf8 x1 = *(const bf8*)(smidb[p] + ar * SMSTR + kk * 32 + koff); if (am) x1 = zero8();
        k[p][0] = MFMA16(x0, b, k[p][0]);
        k[p][1] = MFMA16(x1, b, k[p][1]);
      }
    }
    float kb = rar_kb[m * SIMDIM + t_];
    float part[2][8];
#pragma unroll
    for (int p = 0; p < 2; ++p) {
#pragma unroll
      for (int r = 0; r < 4; ++r) part[p][r] = ftanh(k[p][0][r] + kb) * hq[p];
#pragma unroll
      for (int r = 0; r < 4; ++r)
        part[p][4 + r] = (lg == 0) ? ftanh(k[p][1][r] + kb) * hq[p] : 0.f;
    }
#pragma unroll
    for (int o = 1; o < 16; o <<= 1)
#pragma unroll
      for (int p = 0; p < 2; ++p)
#pragma unroll
        for (int i = 0; i < 8; ++i) part[p][i] += __shfl_xor(part[p][i], o);
    if (lr == 0)
#pragma unroll
      for (int p = 0; p < 2; ++p) {
#pragma unroll
        for (int r = 0; r < 4; ++r) red[p][wv * 20 + lg * 4 + r] = part[p][r];
        if (lg == 0)
#pragma unroll
          for (int r = 0; r < 4; ++r) red[p][wv * 20 + 16 + r] = part[p][4 + r];
      }
  }
  __syncthreads();
  if (tid < 40) {
    int p = tid / 20, q = tid % 20;
    float s = 0.f;
#pragma unroll
    for (int w = 0; w < 16; ++w) s += red[p][w * 20 + q];
    logits[p][q] = s + rar_vb[m];
  }
  __syncthreads();
  if (tid < 128) {  // softmax over q
    int p = tid >> 6;
    float v = (lane < NWORD) ? logits[p][lane] : -1e30f;
    float mx = wmax(v);
    float e = (lane < NWORD) ? __expf(v - mx) : 0.f;
    float s = wsum(e);
    if (lane < NWORD) wsm[p][lane] = e / s;
  }
  __syncthreads();
  if (tid < 512) {
    int p = tid >> 8, t = tid & 255;
    float a = 0.f;
#pragma unroll
    for (int q = 0; q < NWORD; ++q) a += wsm[p][q] * ((const float*)(qsrep[p] + q * QSTR + 512))[t];
    sim_hig[p][t] = a;
  }
  __syncthreads();
  if (tid < 128) {
    int p = tid >> 6;
    float4 v = ((const float4*)sim_hig[p])[lane];
    float s = wsum(d4(v, v));
    if (lane == 0) ssig_s[p] = 1.f / (sqrtf(s) + EPS);
  }
  __syncthreads();

  if (m < 2) {
    if (tid < 512) {
      int p = tid >> 8, t = tid & 255;
      shig_g[(size_t)(pid0 + p) * 256 + t] = sim_hig[p][t] * ssig_s[p];
    }
  } else {
    // final: sigmoid(sim_hig_norm . eval_w + eval_b)
    if (tid < 128) {
      int p = tid >> 6;
      float4 s4v = ((const float4*)sim_hig[p])[lane];
      float4 w4v = ((const float4*)eval_w)[lane];
      float v = wsum(d4(s4v, w4v)) * ssig_s[p];
      if (lane == 0)
        out[pid0 + p] = 1.f / (1.f + __expf(-(v + eval_b[0])));
    }
  }
}

// =================== K2: batched hm+mm GEMM + matrix update ===================
// One block = 4 pairs (M=80 rows, exact 5 tiles, no masking). 16 waves.
// LDS = 80*512*2 = 81920B exactly -> 2 blocks/CU. 2 barriers total.
__global__ __launch_bounds__(1024, 8) void simenc_k2(
    const float* __restrict__ mb1, const float* __restrict__ mb2,
    const u16t* __restrict__ ws,
    const u16t* __restrict__ smid_g, signed char* __restrict__ mat_g,
    int m)
{
  __shared__ __attribute__((aligned(16))) u16t hm_l[80 * 512];   // XOR-swizzled

  const int tid = threadIdx.x;
  const int lane = tid & 63;
  const int wv = tid >> 6;      // 0..15
  const int lr = lane & 15;
  const int lg = lane >> 4;
  const int koff = lg * 8;

  const int pid0 = blockIdx.x * 4;
  const u16t* mw1W = ws + WS_MW1 + (size_t)m * (H1 * SIMDIM);
  const u16t* mw2W = ws + WS_MW2 + (size_t)m * (EMBED * H1);
  const u16t* smidB = smid_g + (size_t)pid0 * 5120;   // 80 contiguous rows of 256

  // ---- phase 1: hm = tanh(smid . mw1^T + mb1); M=80, N=512, K=256 ----
  {
    f4 acc[5][2];
#pragma unroll
    for (int mt = 0; mt < 5; ++mt) { acc[mt][0] = (f4){0,0,0,0}; acc[mt][1] = (f4){0,0,0,0}; }
#pragma unroll 2
    for (int kk = 0; kk < 8; ++kk) {
      bf8 a[5];
#pragma unroll
      for (int mt = 0; mt < 5; ++mt)
        a[mt] = *(const bf8*)(smidB + (size_t)(mt * 16 + lr) * 256 + kk * 32 + koff);
#pragma unroll
      for (int nt = 0; nt < 2; ++nt) {
        bf8 b = *(const bf8*)(mw1W + (size_t)((wv * 2 + nt) * 16 + lr) * 256 + kk * 32 + koff);
#pragma unroll
        for (int mt = 0; mt < 5; ++mt) acc[mt][nt] = MFMA16(a[mt], b, acc[mt][nt]);
      }
    }
#pragma unroll
    for (int nt = 0; nt < 2; ++nt) {
      int j = (wv * 2 + nt) * 16 + lr;
      float bias = mb1[m * H1 + j];
#pragma unroll
      for (int mt = 0; mt < 5; ++mt)
#pragma unroll
        for (int r = 0; r < 4; ++r) {
          int rb = mt * 16 + lg * 4 + r;
          unsigned byteoff = (unsigned)rb * 1024u
                           + (((unsigned)j * 2u) ^ (((unsigned)rb & 7u) << 4));
          *(u16t*)((char*)hm_l + byteoff) = f2bf(ftanh(acc[mt][nt][r] + bias));
        }
    }
  }
  __syncthreads();

  // ---- phase 2: mm = hm . mw2^T + mb2; matrix(int8) = clip(tanh(mm)+matrix) ----
  {
    f4 acc[5][4];
#pragma unroll
    for (int mt = 0; mt < 5; ++mt)
#pragma unroll
      for (int nt = 0; nt < 4; ++nt) acc[mt][nt] = (f4){0,0,0,0};
#pragma unroll 2
    for (int kk = 0; kk < 16; ++kk) {
      bf8 a[5];
#pragma unroll
      for (int mt = 0; mt < 5; ++mt) {
        int rb = mt * 16 + lr;
        unsigned byteoff = (unsigned)rb * 1024u
                         + (((unsigned)(kk * 64 + lg * 16)) ^ (((unsigned)rb & 7u) << 4));
        a[mt] = *(const bf8*)((const char*)hm_l + byteoff);
      }
#pragma unroll
      for (int nt = 0; nt < 4; ++nt) {
        bf8 b = *(const bf8*)(mw2W + (size_t)((wv * 4 + nt) * 16 + lr) * 512 + kk * 32 + koff);
#pragma unroll
        for (int mt = 0; mt < 5; ++mt) acc[mt][nt] = MFMA16(a[mt], b, acc[mt][nt]);
      }
    }
    signed char* matB = mat_g + (size_t)pid0 * 20480;   // 80 contiguous rows of 1024
#pragma unroll
    for (int nt = 0; nt < 4; ++nt) {
      int d = (wv * 4 + nt) * 16 + lr;
      float bias = mb2[m * EMBED + d];
#pragma unroll
      for (int mt = 0; mt < 5; ++mt)
#pragma unroll
        for (int r = 0; r < 4; ++r) {
          int rb = mt * 16 + lg * 4 + r;
          signed char* mp = matB + (size_t)rb * 1024 + d;
          float v = ftanh(acc[mt][nt][r] + bias);
          float mo = (m == 0) ? 1.f : (float)(*mp) * (1.f / 127.f);
          float mn = fminf(fmaxf(v + mo, -1.f), 1.f);
          *mp = (signed char)__float2int_rn(mn * 127.f);
        }
    }
  }
}

// =================== fallback: R7 monolithic (ws too small for split) ===================
__global__ __launch_bounds__(1024, 4) void simenc_mono(
    const float* __restrict__ cap_emb,
    const float* __restrict__ alv_b,
    const float* __restrict__ rar_qw, const float* __restrict__ rar_qb,
    const float* __restrict__ rar_kb,
    const float* __restrict__ rar_vw, const float* __restrict__ rar_vb,
    const float* __restrict__ sb1, const float* __restrict__ sw2, const float* __restrict__ sb2,
    const float* __restrict__ mb1, const float* __restrict__ mb2,
    const float* __restrict__ eval_w, const float* __restrict__ eval_b,
    const u16t* __restrict__ ws,
    float* __restrict__ out)
{
  __shared__ __attribute__((aligned(16))) u16t qsrep[2][NWORD * QSTR];
  __shared__ __attribute__((aligned(16))) u16t smidb[2][NWORD * SMSTR];
  __shared__ __attribute__((aligned(16))) u16t p_bf[2][NWORD * PSTR];
  __shared__ signed char mat8[2][NWORD * 1024];
  __shared__ float attnT[2][NWORD * ATSTR];
  __shared__ float colscale[2][36];
  __shared__ float smoothq[2][NWORD];
  __shared__ float sim_hig[2][SIMDIM];
  __shared__ float red[2][16 * NWORD];
  __shared__ float rq[2][NWORD];
  __shared__ float logits[2][NWORD];
  __shared__ float wsm[2][NWORD];
  __shared__ float ssig_s[2];

  const int tid = threadIdx.x;
  const int lane = tid & 63;
  const int wv = tid >> 6;
  const int lr = lane & 15;
  const int lg = lane >> 4;
  const int koff = lg * 8;

  const int xcd = blockIdx.x & 7;
  const int j_  = blockIdx.x >> 3;
  const int img  = xcd * 8 + (j_ & 7);
  const int cap0 = (j_ >> 3) * 2;

  const float* qryp[2];
  qryp[0] = cap_emb + (size_t)cap0 * (NWORD * EMBED);
  qryp[1] = cap_emb + (size_t)(cap0 + 1) * (NWORD * EMBED);
  const u16t* imgW  = ws + WS_IMG + (size_t)img * (NREG * EMBED);
  const u16t* ctxTW = ws + WS_CTXT + (size_t)img * (EMBED * 64);

#pragma unroll
  for (int p = 0; p < 2; ++p)
#pragma unroll
    for (int q = 0; q < NWORD; ++q) mat8[p][q * 1024 + tid] = 127;
  if (tid < 40) smoothq[tid / 20][tid % 20] = 9.0f;
  __syncthreads();

  for (int m = 0; m < 3; ++m) {
    const u16t* alvW = ws + WS_ALV + (size_t)m * (SIMDIM * EMBED);
    const u16t* kwW  = ws + WS_KW  + (size_t)m * (SIMDIM * SIMDIM);
    const u16t* mw1W = ws + WS_MW1 + (size_t)m * (H1 * SIMDIM);
    const u16t* mw2W = ws + WS_MW2 + (size_t)m * (EMBED * H1);
    const u16t* sw1W = ws + WS_SW1 + (size_t)m * (HSD * SIMDIM);

#pragma unroll
    for (int p = 0; p < 2; ++p) {
      const float* qr = qryp[p];
#pragma unroll 4
      for (int q = 0; q < NWORD; ++q) {
        float mv = (float)mat8[p][q * 1024 + tid] * (1.f / 127.f);
        qsrep[p][q * QSTR + tid] = f2bf(qr[q * 1024 + tid] * mv);
      }
    }
    __syncthreads();

    if (wv < 12) {
      int p = wv / 6, sub = wv % 6;
      int q0 = (sub & 1) * 16, s0 = (sub >> 1) * 16;
      int ari = q0 + lr; bool am = ari >= NWORD; int ar = am ? 0 : ari;
      int bri = s0 + lr; bool bm = bri >= NREG;  int br = bm ? 0 : bri;
      const u16t* ap = qsrep[p] + ar * QSTR + koff;
      const u16t* bp = imgW + (size_t)br * 1024 + koff;
      f4 acc0 = {0.f,0.f,0.f,0.f}, acc1 = {0.f,0.f,0.f,0.f};
#pragma unroll 2
      for (int kk = 0; kk < 32; kk += 2) {
        bf8 a0 = *(const bf8*)(ap + kk * 32);       if (am) a0 = zero8();
        bf8 b0 = *(const bf8*)(bp + kk * 32);       if (bm) b0 = zero8();
        bf8 a1 = *(const bf8*)(ap + (kk + 1) * 32); if (am) a1 = zero8();
        bf8 b1 = *(const bf8*)(bp + (kk + 1) * 32); if (bm) b1 = zero8();
        acc0 = MFMA16(a0, b0, acc0);
        acc1 = MFMA16(a1, b1, acc1);
      }
      f4 acc = acc0 + acc1;
#pragma unroll
      for (int r = 0; r < 4; ++r) {
        int q = q0 + lg * 4 + r, s = s0 + lr;
        if (q < NWORD && s < NREG) {
          float x = acc[r];
          attnT[p][q * ATSTR + s] = (x > 0.f) ? x : 0.1f * x;
        }
      }
    }
    __syncthreads();

    if (tid < 72) {
      int p = tid / 36, s = tid % 36;
      float ss = 0.f;
#pragma unroll
      for (int q = 0; q < NWORD; ++q) { float v = attnT[p][q * ATSTR + s]; ss += v * v; }
      colscale[p][s] = 1.f / (sqrtf(ss) + EPS);
    }
    __syncthreads();

#pragma unroll
    for (int pass = 0; pass < 3; ++pass) {
      int task = wv + pass * 16;
      if (task < 40) {
        int p = task / 20, q = task % 20;
        float x = (lane < NREG)
                ? attnT[p][q * ATSTR + lane] * colscale[p][lane] * smoothq[p][q] : -1e30f;
        float mx = wmax(x);
        float e = (lane < NREG) ? __expf(x - mx) : 0.f;
        float s = wsum(e);
        p_bf[p][q * PSTR + lane] = f2bf(e / s);
      }
    }
    __syncthreads();

    {
      float s2[2][8];
#pragma unroll
      for (int p = 0; p < 2; ++p)
#pragma unroll
        for (int i = 0; i < 8; ++i) s2[p][i] = 0.f;
#pragma unroll
      for (int nt = 0; nt < 4; ++nt) {
        int d0 = wv * 64 + nt * 16;
        const u16t* bp = ctxTW + (size_t)(d0 + lr) * 64 + koff;
        bf8 b0 = *(const bf8*)(bp);
        bf8 b1 = *(const bf8*)(bp + 32);
        int d = d0 + lr;
#pragma unroll
        for (int p = 0; p < 2; ++p)
#pragma unroll
          for (int m2 = 0; m2 < 2; ++m2) {
            int row = m2 * 16 + lr;
            bf8 pa0, pa1;
            if (m2 == 0 || row < NWORD) {
              pa0 = *(const bf8*)(p_bf[p] + row * PSTR + koff);
              pa1 = *(const bf8*)(p_bf[p] + row * PSTR + 32 + koff);
            } else { pa0 = zero8(); pa1 = zero8(); }
            f4 acc = {0.f,0.f,0.f,0.f};
            acc = MFMA16(pa0, b0, acc);
            acc = MFMA16(pa1, b1, acc);
#pragma unroll
            for (int r = 0; r < 4; ++r) {
              int q = m2 * 16 + lg * 4 + r;
              s2[p][m2 * 4 + r] += acc[r] * acc[r];
              if (q < NWORD) qsrep[p][q * QSTR + d] = f2bf(acc[r]);
            }
          }
      }
#pragma unroll
      for (int o = 1; o < 16; o <<= 1)
#pragma unroll
        for (int p = 0; p < 2; ++p)
#pragma unroll
          for (int i = 0; i < 8; ++i) s2[p][i] += __shfl_xor(s2[p][i], o);
      if (lr == 0)
#pragma unroll
        for (int p = 0; p < 2; ++p) {
#pragma unroll
          for (int r = 0; r < 4; ++r) red[p][wv * 20 + lg * 4 + r] = s2[p][r];
          if (lg == 0)
#pragma unroll
            for (int r = 0; r < 4; ++r) red[p][wv * 20 + 16 + r] = s2[p][4 + r];
        }
      __syncthreads();
      if (tid < 40) {
        int p = tid / 20, q = tid % 20;
        float s = 0.f;
#pragma unroll
        for (int w = 0; w < 16; ++w) s += red[p][w * 20 + q];
        rq[p][q] = 1.f / (sqrtf(s) + EPS);
      }
      __syncthreads();
#pragma unroll
      for (int p = 0; p < 2; ++p) {
        const float* qr = qryp[p];
#pragma unroll
        for (int nt = 0; nt < 4; ++nt) {
          int d = wv * 64 + nt * 16 + lr;
#pragma unroll
          for (int m2 = 0; m2 < 2; ++m2)
#pragma unroll
            for (int r = 0; r < 4; ++r) {
              int q = m2 * 16 + lg * 4 + r;
              if (q < NWORD) {
                float wn = bf2f(qsrep[p][q * QSTR + d]) * rq[p][q];
                float t = qr[q * 1024 + d] - wn;
                qsrep[p][q * QSTR + d] = f2bf(t * t);
              }
            }
        }
      }
    }
    __syncthreads();

    {
      int t_ = wv * 16 + lr;
      const u16t* bp = alvW + (size_t)t_ * 1024 + koff;
      int ari = 16 + lr; bool am = ari >= NWORD; int ar = am ? 0 : ari;
      f4 a[2][2];
#pragma unroll
      for (int p = 0; p < 2; ++p) { a[p][0] = (f4){0,0,0,0}; a[p][1] = (f4){0,0,0,0}; }
#pragma unroll 2
      for (int kk = 0; kk < 32; ++kk) {
        bf8 b = *(const bf8*)(bp + kk * 32);
#pragma unroll
        for (int p = 0; p < 2; ++p) {
          bf8 x0 = *(const bf8*)(qsrep[p] + lr * QSTR + kk * 32 + koff);
          bf8 x1 = *(const bf8*)(qsrep[p] + ar * QSTR + kk * 32 + koff); if (am) x1 = zero8();
          a[p][0] = MFMA16(x0, b, a[p][0]);
          a[p][1] = MFMA16(x1, b, a[p][1]);
        }
      }
      float bias = alv_b[m * SIMDIM + t_];
      float s2[2][8];
#pragma unroll
      for (int p = 0; p < 2; ++p) {
#pragma unroll
        for (int r = 0; r < 4; ++r) { a[p][0][r] += bias; s2[p][r] = a[p][0][r] * a[p][0][r]; }
#pragma unroll
        for (int r = 0; r < 4; ++r) {
          a[p][1][r] += bias;
          s2[p][4 + r] = (lg == 0) ? a[p][1][r] * a[p][1][r] : 0.f;
        }
      }
#pragma unroll
      for (int o = 1; o < 16; o <<= 1)
#pragma unroll
        for (int p = 0; p < 2; ++p)
#pragma unroll
          for (int i = 0; i < 8; ++i) s2[p][i] += __shfl_xor(s2[p][i], o);
      if (lr == 0)
#pragma unroll
        for (int p = 0; p < 2; ++p) {
#pragma unroll
          for (int r = 0; r < 4; ++r) red[p][wv * 20 + lg * 4 + r] = s2[p][r];
          if (lg == 0)
#pragma unroll
            for (int r = 0; r < 4; ++r) red[p][wv * 20 + 16 + r] = s2[p][4 + r];
        }
      __syncthreads();
      if (tid < 40) {
        int p = tid / 20, q = tid % 20;
        float s = 0.f;
#pragma unroll
        for (int w = 0; w < 16; ++w) s += red[p][w * 20 + q];
        rq[p][q] = 1.f / (sqrtf(s) + EPS);
      }
      __syncthreads();
#pragma unroll
      for (int p = 0; p < 2; ++p) {
#pragma unroll
        for (int r = 0; r < 4; ++r) {
          int q = lg * 4 + r;
          float v = a[p][0][r] * rq[p][q];
          ((float*)(qsrep[p] + q * QSTR + 512))[t_] = v;
          smidb[p][q * SMSTR + t_] = f2bf(v);
        }
        if (lg == 0)
#pragma unroll
          for (int r = 0; r < 4; ++r) {
            int q = 16 + r;
            float v = a[p][1][r] * rq[p][q];
            ((float*)(qsrep[p] + q * QSTR + 512))[t_] = v;
            smidb[p][q * SMSTR + t_] = f2bf(v);
          }
      }
    }
    __syncthreads();

    if (m == 0 && tid < 512) {
      int p = tid / 256, t = tid % 256;
      float s = 0.f;
#pragma unroll
      for (int q = 0; q < NWORD; ++q) s += ((const float*)(qsrep[p] + q * QSTR + 512))[t];
      sim_hig[p][t] = s * (1.f / NWORD);
    }
    __syncthreads();

    if (m < 2) {
      {
        int ari = 16 + lr; bool am = ari >= NWORD; int ar = am ? 0 : ari;
#pragma unroll
        for (int nt = 0; nt < 2; ++nt) {
          int j0 = (wv * 2 + nt) * 16;
          f4 h[2][2];
#pragma unroll
          for (int p = 0; p < 2; ++p) { h[p][0] = (f4){0,0,0,0}; h[p][1] = (f4){0,0,0,0}; }
#pragma unroll 2
          for (int kk = 0; kk < 8; ++kk) {
            bf8 b = *(const bf8*)(mw1W + (size_t)(j0 + lr) * 256 + kk * 32 + koff);
#pragma unroll
            for (int p = 0; p < 2; ++p) {
              bf8 x0 = *(const bf8*)(smidb[p] + lr * SMSTR + kk * 32 + koff);
              bf8 x1 = *(const bf8*)(smidb[p] + ar * SMSTR + kk * 32 + koff); if (am) x1 = zero8();
              h[p][0] = MFMA16(x0, b, h[p][0]);
              h[p][1] = MFMA16(x1, b, h[p][1]);
            }
          }
          int j = j0 + lr;
          float bias = mb1[m * H1 + j];
#pragma unroll
          for (int p = 0; p < 2; ++p) {
#pragma unroll
            for (int r = 0; r < 4; ++r) {
              int q = lg * 4 + r;
              qsrep[p][q * QSTR + j] = f2bf(ftanh(h[p][0][r] + bias));
            }
            if (lg == 0)
#pragma unroll
              for (int r = 0; r < 4; ++r)
                qsrep[p][(16 + r) * QSTR + j] = f2bf(ftanh(h[p][1][r] + bias));
          }
        }
      }
      __syncthreads();
      {
        int ari = 16 + lr; bool am = ari >= NWORD; int ar = am ? 0 : ari;
#pragma unroll
        for (int nt = 0; nt < 4; ++nt) {
          int d0 = wv * 64 + nt * 16;
          f4 c[2][2];
#pragma unroll
          for (int p = 0; p < 2; ++p) { c[p][0] = (f4){0,0,0,0}; c[p][1] = (f4){0,0,0,0}; }
#pragma unroll 2
          for (int kk = 0; kk < 16; ++kk) {
            bf8 b = *(const bf8*)(mw2W + (size_t)(d0 + lr) * 512 + kk * 32 + koff);
#pragma unroll
            for (int p = 0; p < 2; ++p) {
              bf8 x0 = *(const bf8*)(qsrep[p] + lr * QSTR + kk * 32 + koff);
              bf8 x1 = *(const bf8*)(qsrep[p] + ar * QSTR + kk * 32 + koff); if (am) x1 = zero8();
              c[p][0] = MFMA16(x0, b, c[p][0]);
              c[p][1] = MFMA16(x1, b, c[p][1]);
            }
          }
          int d = d0 + lr;
          float bias = mb2[m * EMBED + d];
#pragma unroll
          for (int p = 0; p < 2; ++p) {
#pragma unroll
            for (int r = 0; r < 4; ++r) {
              int q = lg * 4 + r;
              float v = ftanh(c[p][0][r] + bias);
              float mo = (float)mat8[p][q * 1024 + d] * (1.f / 127.f);
              float mn = fminf(fmaxf(v + mo, -1.f), 1.f);
              mat8[p][q * 1024 + d] = (signed char)__float2int_rn(mn * 127.f);
            }
            if (lg == 0)
#pragma unroll
              for (int r = 0; r < 4; ++r) {
                int q = 16 + r;
                float v = ftanh(c[p][1][r] + bias);
                float mo = (float)mat8[p][q * 1024 + d] * (1.f / 127.f);
                float mn = fminf(fmaxf(v + mo, -1.f), 1.f);
                mat8[p][q * 1024 + d] = (signed char)__float2int_rn(mn * 127.f);
              }
          }
        }
      }
      {
        if (wv < 8) {
          int j0 = wv * 16;
          int ari = 16 + lr; bool am = ari >= NWORD; int ar = am ? 0 : ari;
          f4 h[2][2];
#pragma unroll
          for (int p = 0; p < 2; ++p) { h[p][0] = (f4){0,0,0,0}; h[p][1] = (f4){0,0,0,0}; }
#pragma unroll 2
          for (int kk = 0; kk < 8; ++kk) {
            bf8 b = *(const bf8*)(sw1W + (size_t)(j0 + lr) * 256 + kk * 32 + koff);
#pragma unroll
            for (int p = 0; p < 2; ++p) {
              bf8 x0 = *(const bf8*)(smidb[p] + lr * SMSTR + kk * 32 + koff);
              bf8 x1 = *(const bf8*)(smidb[p] + ar * SMSTR + kk * 32 + koff); if (am) x1 = zero8();
              h[p][0] = MFMA16(x0, b, h[p][0]);
              h[p][1] = MFMA16(x1, b, h[p][1]);
            }
          }
          int j = j0 + lr;
          float bias = sb1[m * HSD + j];
          float s2v = sw2[m * HSD + j];
          float part[2][8];
#pragma unroll
          for (int p = 0; p < 2; ++p) {
#pragma unroll
            for (int r = 0; r < 4; ++r) part[p][r] = ftanh(h[p][0][r] + bias) * s2v;
#pragma unroll
            for (int r = 0; r < 4; ++r)
              part[p][4 + r] = (lg == 0) ? ftanh(h[p][1][r] + bias) * s2v : 0.f;
          }
#pragma unroll
          for (int o = 1; o < 16; o <<= 1)
#pragma unroll
            for (int p = 0; p < 2; ++p)
#pragma unroll
              for (int i = 0; i < 8; ++i) part[p][i] += __shfl_xor(part[p][i], o);
          if (lr == 0)
#pragma unroll
            for (int p = 0; p < 2; ++p) {
#pragma unroll
              for (int r = 0; r < 4; ++r) red[p][wv * 20 + lg * 4 + r] = part[p][r];
              if (lg == 0)
#pragma unroll
                for (int r = 0; r < 4; ++r) red[p][wv * 20 + 16 + r] = part[p][4 + r];
            }
        }
      }
      __syncthreads();
      if (tid < 40) {
        int p = tid / 20, q = tid % 20;
        float s = 0.f;
#pragma unroll
        for (int w = 0; w < 8; ++w) s += red[p][w * 20 + q];
        smoothq[p][q] = fmaxf(0.f, s + sb2[m] + smoothq[p][q]);
      }
      __syncthreads();
    }

    {
      int t_ = wv * 16 + lr;
      int ari = 16 + lr; bool am = ari >= NWORD; int ar = am ? 0 : ari;
      float hq[2];
#pragma unroll
      for (int p = 0; p < 2; ++p) {
        const float4* wq = (const float4*)(rar_qw + ((size_t)m * SIMDIM + t_) * SIMDIM);
        const float4* sh = (const float4*)sim_hig[p];
        float hacc = 0.f;
#pragma unroll 2
        for (int i = 0; i < SIMDIM / 4; ++i) hacc += d4(wq[i], sh[i]);
        hq[p] = ftanh(hacc + rar_qb[m * SIMDIM + t_]) * rar_vw[m * SIMDIM + t_];
      }
      f4 k[2][2];
#pragma unroll
      for (int p = 0; p < 2; ++p) { k[p][0] = (f4){0,0,0,0}; k[p][1] = (f4){0,0,0,0}; }
#pragma unroll 2
      for (int kk = 0; kk < 8; ++kk) {
        bf8 b = *(const bf8*)(kwW + (size_t)t_ * 256 + kk * 32 + koff);
#pragma unroll
        for (int p = 0; p < 2; ++p) {
          bf8 x0 = *(const bf8*)(smidb[p] + lr * SMSTR + kk * 32 + koff);
          bf8 x1 = *(const bf8*)(smidb[p] + ar * SMSTR + kk * 32 + koff); if (am) x1 = zero8();
          k[p][0] = MFMA16(x0, b, k[p][0]);
          k[p][1] = MFMA16(x1, b, k[p][1]);
        }
      }
      float kb = rar_kb[m * SIMDIM + t_];
      float part[2][8];
#pragma unroll
      for (int p = 0; p < 2; ++p) {
#pragma unroll
        for (int r = 0; r < 4; ++r) part[p][r] = ftanh(k[p][0][r] + kb) * hq[p];
#pragma unroll
        for (int r = 0; r < 4; ++r)
          part[p][4 + r] = (lg == 0) ? ftanh(k[p][1][r] + kb) * hq[p] : 0.f;
      }
#pragma unroll
      for (int o = 1; o < 16; o <<= 1)
#pragma unroll
        for (int p = 0; p < 2; ++p)
#pragma unroll
          for (int i = 0; i < 8; ++i) part[p][i] += __shfl_xor(part[p][i], o);
      if (lr == 0)
#pragma unroll
        for (int p = 0; p < 2; ++p) {
#pragma unroll
          for (int r = 0; r < 4; ++r) red[p][wv * 20 + lg * 4 + r] = part[p][r];
          if (lg == 0)
#pragma unroll
            for (int r = 0; r < 4; ++r) red[p][wv * 20 + 16 + r] = part[p][4 + r];
        }
    }
    __syncthreads();
    if (tid < 40) {
      int p = tid / 20, q = tid % 20;
      float s = 0.f;
#pragma unroll
      for (int w = 0; w < 16; ++w) s += red[p][w * 20 + q];
      logits[p][q] = s + rar_vb[m];
    }
    __syncthreads();
    if (tid < 128) {
      int p = tid >> 6;
      float v = (lane < NWORD) ? logits[p][lane] : -1e30f;
      float mx = wmax(v);
      float e = (lane < NWORD) ? __expf(v - mx) : 0.f;
      float s = wsum(e);
      if (lane < NWORD) wsm[p][lane] = e / s;
    }
    __syncthreads();
    if (tid < 512) {
      int p = tid / 256, t = tid % 256;
      float a = 0.f;
#pragma unroll
      for (int q = 0; q < NWORD; ++q) a += wsm[p][q] * ((const float*)(qsrep[p] + q * QSTR + 512))[t];
      sim_hig[p][t] = a;
    }
    __syncthreads();
    if (tid < 128) {
      int p = tid >> 6;
      float4 v = ((const float4*)sim_hig[p])[lane];
      float s = wsum(d4(v, v));
      if (lane == 0) ssig_s[p] = 1.f / (sqrtf(s) + EPS);
    }
    __syncthreads();
    if (tid < 512) {
      int p = tid / 256, t = tid % 256;
      sim_hig[p][t] *= ssig_s[p];
    }
    __syncthreads();
  }

  if (tid < 128) {
    int p = tid >> 6;
    float4 s4v = ((const float4*)sim_hig[p])[lane];
    float4 w4v = ((const float4*)eval_w)[lane];
    float v = wsum(d4(s4v, w4v));
    if (lane == 0)
      out[img * NCAP + cap0 + p] = 1.f / (1.f + __expf(-(v + eval_b[0])));
  }
}

// ---------------- fallback: f32 VALU kernel (no usable ws) ----------------
__global__ __launch_bounds__(1024) void simenc_valu(
    const float* __restrict__ img_emb, const float* __restrict__ cap_emb,
    const float* __restrict__ alv_w,  const float* __restrict__ alv_b,
    const float* __restrict__ rar_qw, const float* __restrict__ rar_qb,
    const float* __restrict__ rar_kw, const float* __restrict__ rar_kb,
    const float* __restrict__ rar_vw, const float* __restrict__ rar_vb,
    const float* __restrict__ sw1, const float* __restrict__ sb1,
    const float* __restrict__ sw2, const float* __restrict__ sb2,
    const float* __restrict__ mw1, const float* __restrict__ mb1,
    const float* __restrict__ mw2, const float* __restrict__ mb2,
    const float* __restrict__ eval_w, const float* __restrict__ eval_b,
    float* __restrict__ out)
{
  __shared__ float buf[NWORD * EMBED];
  __shared__ float smid[NWORD * SIMDIM];
  __shared__ float attn_raw[NREG * NWORD];
  __shared__ float attnT[NWORD * NREG];
  __shared__ float smoothq[NWORD];
  __shared__ float sim_hig[SIMDIM];
  __shared__ float hqu[SIMDIM];
  __shared__ float wsm_[NWORD];
  __shared__ float red[16 * NWORD];
  __shared__ float rq[NWORD];
  __shared__ float ssig;

  const int tid = threadIdx.x;
  const int lane = tid & 63;
  const int wv = tid >> 6;
  const int pair = blockIdx.x;
  const int img = pair & 63;
  const int cap = pair >> 6;
  const float* ctx = img_emb + (size_t)img * (NREG * EMBED);
  const float* qry = cap_emb + (size_t)cap * (NWORD * EMBED);

  float mat[NWORD];
#pragma unroll
  for (int q = 0; q < NWORD; ++q) mat[q] = 1.f;
  if (tid < NWORD) smoothq[tid] = 9.f;
  __syncthreads();

  for (int m = 0; m < 3; ++m) {
#pragma unroll 4
    for (int q = 0; q < NWORD; ++q)
      buf[q * EMBED + tid] = qry[q * EMBED + tid] * mat[q];
    __syncthreads();
    if (tid < NWORD * NREG) {
      int q = tid / NREG, s = tid % NREG;
      const float4* c4 = (const float4*)(ctx + s * EMBED);
      const float4* q4 = (const float4*)(buf + q * EMBED);
      float acc = 0.f;
#pragma unroll 4
      for (int i = 0; i < EMBED / 4; ++i) acc += d4(c4[i], q4[i]);
      attn_raw[s * NWORD + q] = (acc > 0.f) ? acc : 0.1f * acc;
    }
    __syncthreads();
    if (tid < NREG) {
      int s = tid; float sumsq = 0.f;
#pragma unroll
      for (int q = 0; q < NWORD; ++q) { float v = attn_raw[s * NWORD + q]; sumsq += v * v; }
      float sc = 1.f / (sqrtf(sumsq) + EPS);
#pragma unroll
      for (int q = 0; q < NWORD; ++q) attnT[q * NREG + s] = attn_raw[s * NWORD + q] * sc;
    }
    __syncthreads();
    if (tid < NWORD) {
      int q = tid; float sm = smoothq[q]; float mx = -1e30f;
      for (int s = 0; s < NREG; ++s) mx = fmaxf(mx, attnT[q * NREG + s] * sm);
      float sum = 0.f;
      for (int s = 0; s < NREG; ++s) { float e = __expf(attnT[q * NREG + s] * sm - mx); attnT[q * NREG + s] = e; sum += e; }
      float r = 1.f / sum;
      for (int s = 0; s < NREG; ++s) attnT[q * NREG + s] *= r;
    }
    __syncthreads();
    {
      float wacc[NWORD];
#pragma unroll
      for (int q = 0; q < NWORD; ++q) wacc[q] = 0.f;
#pragma unroll
      for (int sc_ = 0; sc_ < 3; ++sc_) {
        float c[12];
#pragma unroll
        for (int i = 0; i < 12; ++i) c[i] = ctx[(sc_ * 12 + i) * EMBED + tid];
#pragma unroll
        for (int q = 0; q < NWORD; ++q) {
          const float4* a4 = (const float4*)(attnT + q * NREG + sc_ * 12);
          float4 a0 = a4[0], a1 = a4[1], a2 = a4[2];
          wacc[q] += a0.x*c[0] + a0.y*c[1] + a0.z*c[2] + a0.w*c[3]
                   + a1.x*c[4] + a1.y*c[5] + a1.z*c[6] + a1.w*c[7]
                   + a2.x*c[8] + a2.y*c[9] + a2.z*c[10] + a2.w*c[11];
        }
      }
#pragma unroll
      for (int q = 0; q < NWORD; ++q) {
        float v = wsum(wacc[q] * wacc[q]);
        if (lane == 0) red[wv * NWORD + q] = v;
      }
      __syncthreads();
      if (tid < NWORD) {
        float s = 0.f;
#pragma unroll
        for (int w = 0; w < 16; ++w) s += red[w * NWORD + tid];
        rq[tid] = 1.f / (sqrtf(s) + EPS);
      }
      __syncthreads();
#pragma unroll 4
      for (int q = 0; q < NWORD; ++q) {
        float wn = wacc[q] * rq[q];
        float t = qry[q * EMBED + tid] - wn;
        buf[q * EMBED + tid] = t * t;
      }
    }
    __syncthreads();
    {
      int t = tid & 255, g = tid >> 8;
      const float4* w4 = (const float4*)(alv_w + ((size_t)m * SIMDIM + t) * EMBED);
      float acc[5] = {0, 0, 0, 0, 0};
      for (int i = 0; i < EMBED / 4; ++i) {
        float4 w = w4[i];
#pragma unroll
        for (int k = 0; k < 5; ++k) acc[k] += d4(w, ((const float4*)(buf + (g + 4 * k) * EMBED))[i]);
      }
      float b = alv_b[m * SIMDIM + t];
#pragma unroll
      for (int k = 0; k < 5; ++k) smid[(g + 4 * k) * SIMDIM + t] = acc[k] + b;
    }
    __syncthreads();
#pragma unroll
    for (int rep = 0; rep < 2; ++rep) {
      int q = wv + rep * 16;
      if (q < NWORD) {
        float4 v = ((const float4*)(smid + q * SIMDIM))[lane];
        float s = wsum(d4(v, v));
        if (lane == 0) rq[q] = 1.f / (sqrtf(s) + EPS);
      }
    }
    __syncthreads();
#pragma unroll
    for (int k = 0; k < 5; ++k) { int e = tid + k * 1024; smid[e] *= rq[e >> 8]; }
    __syncthreads();
    if (m == 0 && tid < SIMDIM) {
      float s = 0.f;
#pragma unroll
      for (int q = 0; q < NWORD; ++q) s += smid[q * SIMDIM + tid];
      sim_hig[tid] = s * (1.f / NWORD);
    }
    __syncthreads();
    if (m < 2) {
      {
        int j = tid & 511, g = tid >> 9;
        const float4* w4 = (const float4*)(mw1 + ((size_t)m * H1 + j) * SIMDIM);
        float acc[10];
#pragma unroll
        for (int k = 0; k < 10; ++k) acc[k] = 0.f;
        for (int i = 0; i < SIMDIM / 4; ++i) {
          float4 w = w4[i];
#pragma unroll
          for (int k = 0; k < 10; ++k) acc[k] += d4(w, ((const float4*)(smid + (g + 2 * k) * SIMDIM))[i]);
        }
        float b = mb1[m * H1 + j];
#pragma unroll
        for (int k = 0; k < 10; ++k) buf[(g + 2 * k) * H1 + j] = ftanh(acc[k] + b);
      }
      __syncthreads();
      {
        const float4* w4 = (const float4*)(mw2 + ((size_t)m * EMBED + tid) * H1);
        float acc[NWORD];
#pragma unroll
        for (int q = 0; q < NWORD; ++q) acc[q] = 0.f;
        for (int i = 0; i < H1 / 4; ++i) {
          float4 w = w4[i];
#pragma unroll
          for (int q = 0; q < NWORD; ++q) acc[q] += d4(w, ((const float4*)(buf + q * H1))[i]);
        }
        float b = mb2[m * EMBED + tid];
#pragma unroll
        for (int q = 0; q < NWORD; ++q)
          mat[q] = fminf(fmaxf(ftanh(acc[q] + b) + mat[q], -1.f), 1.f);
      }
      {
        int j = tid & 127, g = tid >> 7;
        const float4* w4 = (const float4*)(sw1 + ((size_t)m * HSD + j) * SIMDIM);
        float a0 = 0.f, a1 = 0.f, a2 = 0.f;
        for (int i = 0; i < SIMDIM / 4; ++i) {
          float4 w = w4[i];
          a0 += d4(w, ((const float4*)(smid + g * SIMDIM))[i]);
          a1 += d4(w, ((const float4*)(smid + (g + 8) * SIMDIM))[i]);
          if (g < 4) a2 += d4(w, ((const float4*)(smid + (g + 16) * SIMDIM))[i]);
        }
        float b = sb1[m * HSD + j];
        buf[10240 + g * HSD + j] = ftanh(a0 + b);
        buf[10240 + (g + 8) * HSD + j] = ftanh(a1 + b);
        if (g < 4) buf[10240 + (g + 16) * HSD + j] = ftanh(a2 + b);
      }
      __syncthreads();
      {
        const float* sw2m = sw2 + m * HSD;
#pragma unroll
        for (int rep = 0; rep < 2; ++rep) {
          int q = wv + rep * 16;
          if (q < NWORD) {
            float v = buf[10240 + q * HSD + lane] * sw2m[lane]
                    + buf[10240 + q * HSD + 64 + lane] * sw2m[64 + lane];
            v = wsum(v);
            if (lane == 0) smoothq[q] = fmaxf(0.f, v + sb2[m] + smoothq[q]);
          }
        }
      }
      __syncthreads();
    }
    {
      int t = tid & 255, g = tid >> 8;
      const float4* w4 = (const float4*)(rar_kw + ((size_t)m * SIMDIM + t) * SIMDIM);
      float acc[5] = {0, 0, 0, 0, 0};
      for (int i = 0; i < SIMDIM / 4; ++i) {
        float4 w = w4[i];
#pragma unroll
        for (int k = 0; k < 5; ++k) acc[k] += d4(w, ((const float4*)(smid + (g + 4 * k) * SIMDIM))[i]);
      }
      float b = rar_kb[m * SIMDIM + t];
#pragma unroll
      for (int k = 0; k < 5; ++k) buf[12800 + (g + 4 * k) * SIMDIM + t] = ftanh(acc[k] + b);
    }
    if (tid < SIMDIM) {
      const float4* w4 = (const float4*)(rar_qw + ((size_t)m * SIMDIM + tid) * SIMDIM);
      const float4* s4 = (const float4*)sim_hig;
      float acc = 0.f;
      for (int i = 0; i < SIMDIM / 4; ++i) acc += d4(w4[i], s4[i]);
      hqu[tid] = ftanh(acc + rar_qb[m * SIMDIM + tid]) * rar_vw[m * SIMDIM + tid];
    }
    __syncthreads();
#pragma unroll
    for (int rep = 0; rep < 2; ++rep) {
      int q = wv + rep * 16;
      if (q < NWORD) {
        float4 a = ((const float4*)(buf + 12800 + q * SIMDIM))[lane];
        float4 u = ((const float4*)hqu)[lane];
        float v = wsum(d4(a, u));
        if (lane == 0) red[q] = v + rar_vb[m];
      }
    }
    __syncthreads();
    if (tid < 64) {
      float v = (tid < NWORD) ? red[tid] : -1e30f;
      float mx = wmax(v);
      float e = (tid < NWORD) ? __expf(v - mx) : 0.f;
      float s = wsum(e);
      if (tid < NWORD) wsm_[tid] = e / s;
    }
    __syncthreads();
    if (tid < SIMDIM) {
      float acc = 0.f;
#pragma unroll
      for (int q = 0; q < NWORD; ++q) acc += wsm_[q] * smid[q * SIMDIM + tid];
      sim_hig[tid] = acc;
    }
    __syncthreads();
    if (tid < 64) {
      float4 v = ((const float4*)sim_hig)[tid];
      float s = wsum(d4(v, v));
      if (tid == 0) ssig = 1.f / (sqrtf(s) + EPS);
    }
    __syncthreads();
    if (tid < SIMDIM) sim_hig[tid] *= ssig;
    __syncthreads();
  }
  if (tid < 64) {
    float4 s4v = ((const float4*)sim_hig)[tid];
    float4 w4v = ((const float4*)eval_w)[tid];
    float v = wsum(d4(s4v, w4v));
    if (tid == 0) out[img * NCAP + cap] = 1.f / (1.f + __expf(-(v + eval_b[0])));
  }
}

extern "C" void kernel_launch(void* const* d_in, const int* in_sizes, int n_in,
                              void* d_out, int out_size, void* d_ws, size_t ws_size,
                              hipStream_t stream) {
  (void)in_sizes; (void)n_in; (void)out_size;
  const size_t WS_WEIGHTS = (size_t)WS_END * 2u;
  u16t* ws = (u16t*)d_ws;

  if (ws_size >= (size_t)WS_FULL_BYTES) {
    cvt_kernel<<<2048, 1024, 0, stream>>>(
        (const float*)d_in[3],  (const float*)d_in[7],  (const float*)d_in[15],
        (const float*)d_in[17], (const float*)d_in[11], (const float*)d_in[0], ws);
    ctxt_kernel<<<1024, 256, 0, stream>>>((const float*)d_in[0], ws + WS_CTXT);

    signed char* mat_g = (signed char*)d_ws + OFFB_MAT;
    u16t*  smid_g   = (u16t*)((char*)d_ws + OFFB_SMID);
    float* shig_g   = (float*)((char*)d_ws + OFFB_SHIG);
    float* smooth_g = (float*)((char*)d_ws + OFFB_SMOOTH);

    for (int m = 0; m < 3; ++m) {
      simenc_k1<<<NIMG * NCAP / 2, 1024, 0, stream>>>(
          (const float*)d_in[1],  (const float*)d_in[4],
          (const float*)d_in[5],  (const float*)d_in[6],  (const float*)d_in[8],
          (const float*)d_in[9],  (const float*)d_in[10],
          (const float*)d_in[12], (const float*)d_in[13], (const float*)d_in[14],
          (const float*)d_in[19], (const float*)d_in[20],
          ws, mat_g, smid_g, shig_g, smooth_g, m, (float*)d_out);
      if (m < 2)
        simenc_k2<<<NIMG * NCAP / 4, 1024, 0, stream>>>(
            (const float*)d_in[16], (const float*)d_in[18],
            ws, smid_g, mat_g, m);
    }
  } else if (ws_size >= WS_WEIGHTS) {
    cvt_kernel<<<2048, 1024, 0, stream>>>(
        (const float*)d_in[3],  (const float*)d_in[7],  (const float*)d_in[15],
        (const float*)d_in[17], (const float*)d_in[11], (const float*)d_in[0], ws);
    ctxt_kernel<<<1024, 256, 0, stream>>>((const float*)d_in[0], ws + WS_CTXT);
    simenc_mono<<<NIMG * NCAP / 2, 1024, 0, stream>>>(
        (const float*)d_in[1],
        (const float*)d_in[4],
        (const float*)d_in[5],  (const float*)d_in[6],
        (const float*)d_in[8],
        (const float*)d_in[9],  (const float*)d_in[10],
        (const float*)d_in[12], (const float*)d_in[13], (const float*)d_in[14],
        (const float*)d_in[16], (const float*)d_in[18],
        (const float*)d_in[19], (const float*)d_in[20],
        ws, (float*)d_out);
  } else {
    simenc_valu<<<NIMG * NCAP, 1024, 0, stream>>>(
        (const float*)d_in[0],  (const float*)d_in[1],
        (const float*)d_in[3],  (const float*)d_in[4],
        (const float*)d_in[5],  (const float*)d_in[6],
        (const float*)d_in[7],  (const float*)d_in[8],
        (const float*)d_in[9],  (const float*)d_in[10],
        (const float*)d_in[11], (const float*)d_in[12],
        (const float*)d_in[13], (const float*)d_in[14],
        (const float*)d_in[15], (const float*)d_in[16],
        (const float*)d_in[17], (const float*)d_in[18],
        (const float*)d_in[19], (const float*)d_in[20],
        (float*)d_out);
  }
}

// Round 10
// 3424.792 us; speedup vs baseline: 1.9620x; 1.9620x over previous
//
#include <hip/hip_runtime.h>
#include <math.h>

#define NIMG 64
#define NCAP 64
#define NREG 36      // S: image regions
#define NWORD 20     // Q: caption words
#define EMBED 1024   // D
#define SIMDIM 256   // SIM
#define H1 512       // rcr matrix-MLP hidden
#define HSD 128      // rcr smooth-MLP hidden
#define EPS 1e-8f

// padded LDS row strides (u16 units)
#define QSTR 1032
#define SMSTR 264
#define PSTR 72
#define ATSTR 37

typedef unsigned short u16t;
typedef __bf16 bf8 __attribute__((ext_vector_type(8)));
typedef short  s8i __attribute__((ext_vector_type(8)));
typedef float  f4  __attribute__((ext_vector_type(4)));

__device__ __forceinline__ float wsum(float v) {
#pragma unroll
  for (int o = 32; o > 0; o >>= 1) v += __shfl_xor(v, o);
  return v;
}
__device__ __forceinline__ float wmax(float v) {
#pragma unroll
  for (int o = 32; o > 0; o >>= 1) v = fmaxf(v, __shfl_xor(v, o));
  return v;
}
__device__ __forceinline__ float ftanh(float x) {
  x = fminf(fmaxf(x, -15.f), 15.f);
  float e = __expf(2.f * x);
  return (e - 1.f) / (e + 1.f);
}
__device__ __forceinline__ float d4(float4 a, float4 b) {
  return a.x*b.x + a.y*b.y + a.z*b.z + a.w*b.w;
}
__device__ __forceinline__ u16t f2bf(float f) {
  unsigned u = __float_as_uint(f);
  u += 0x7FFFu + ((u >> 16) & 1u);
  return (u16t)(u >> 16);
}
__device__ __forceinline__ float bf2f(u16t h) { return __uint_as_float(((unsigned)h) << 16); }
__device__ __forceinline__ bf8 zero8() {
  s8i z = {0,0,0,0,0,0,0,0};
  return __builtin_bit_cast(bf8, z);
}
#define MFMA16(a, b, c) __builtin_amdgcn_mfma_f32_16x16x32_bf16((a), (b), (c), 0, 0, 0)

// d_ws layout (u16 elements) for weights
#define WS_ALV   0u
#define WS_KW    786432u
#define WS_MW1   983040u
#define WS_MW2   1245184u
#define WS_SW1   2293760u
#define WS_IMG   2359296u
#define WS_CTXT  4718592u
#define WS_END   8912896u
#define N_CVT    4718592u

// byte offsets of inter-kernel state (after weights)
#define OFFB_MAT    17825792ull                 // int8 [4096][20][1024] = 83886080
#define OFFB_SMID   (OFFB_MAT + 83886080ull)    // u16  [4096][20][256] = 41943040
#define OFFB_SHIG   (OFFB_SMID + 41943040ull)   // f32  [4096][256]     = 4194304
#define OFFB_SMOOTH (OFFB_SHIG + 4194304ull)    // f32  [4096][20]      = 327680
#define WS_FULL_BYTES (OFFB_SMOOTH + 327680ull) // ~148.2 MB

// ---------------- pre-pass 1: weights + img -> bf16 ----------------
__global__ void cvt_kernel(const float* __restrict__ alv, const float* __restrict__ kw,
                           const float* __restrict__ mw1, const float* __restrict__ mw2,
                           const float* __restrict__ sw1, const float* __restrict__ img,
                           u16t* __restrict__ ws) {
  for (unsigned i = blockIdx.x * blockDim.x + threadIdx.x; i < N_CVT; i += gridDim.x * blockDim.x) {
    unsigned o = i; float v;
    if (o < 786432u) v = alv[o];
    else if ((o -= 786432u) < 196608u) v = kw[o];
    else if ((o -= 196608u) < 262144u) v = mw1[o];
    else if ((o -= 262144u) < 1048576u) v = mw2[o];
    else if ((o -= 1048576u) < 65536u) v = sw1[o];
    else { o -= 65536u; v = img[o]; }
    ws[i] = f2bf(v);
  }
}

// ---------------- pre-pass 2: ctxT[img][d][s(pad 64)] bf16 ----------------
__global__ void ctxt_kernel(const float* __restrict__ img, u16t* __restrict__ ctxT) {
  __shared__ float tile[36 * 65];
  int b = blockIdx.x;
  int im = b >> 4, dt = (b & 15) * 64;
  const float* src = img + (size_t)im * 36 * 1024 + dt;
  for (int e = threadIdx.x; e < 36 * 64; e += 256) {
    int s = e >> 6, dd = e & 63;
    tile[s * 65 + dd] = src[s * 1024 + dd];
  }
  __syncthreads();
  u16t* dst = ctxT + (size_t)im * 65536 + dt * 64;
  for (int o = threadIdx.x; o < 4096; o += 256) {
    int dd = o >> 6, sp = o & 63;
    dst[dd * 64 + sp] = (sp < 36) ? f2bf(tile[sp * 65 + dd]) : (u16t)0;
  }
}

// =================== K1: attention + F + regulators (per 2 pairs) ===================
__global__ __launch_bounds__(1024, 4) void simenc_k1(
    const float* __restrict__ cap_emb,
    const float* __restrict__ alv_b,
    const float* __restrict__ rar_qw, const float* __restrict__ rar_qb,
    const float* __restrict__ rar_kb,
    const float* __restrict__ rar_vw, const float* __restrict__ rar_vb,
    const float* __restrict__ sb1, const float* __restrict__ sw2, const float* __restrict__ sb2,
    const float* __restrict__ eval_w, const float* __restrict__ eval_b,
    const u16t* __restrict__ ws,
    signed char* __restrict__ mat_g, u16t* __restrict__ smid_g,
    float* __restrict__ shig_g, float* __restrict__ smooth_g,
    int m, float* __restrict__ out)
{
  __shared__ __attribute__((aligned(16))) u16t qsrep[2][NWORD * QSTR];
  __shared__ __attribute__((aligned(16))) u16t smidb[2][NWORD * SMSTR];
  __shared__ __attribute__((aligned(16))) u16t p_bf[2][NWORD * PSTR];
  __shared__ float attnT[2][NWORD * ATSTR];
  __shared__ float colscale[2][36];
  __shared__ float smoothq[2][NWORD];
  __shared__ float sim_hig[2][SIMDIM];
  __shared__ float red[2][16 * NWORD];
  __shared__ float rq[2][NWORD];
  __shared__ float logits[2][NWORD];
  __shared__ float wsm[2][NWORD];
  __shared__ float ssig_s[2];

  const int tid = threadIdx.x;
  const int lane = tid & 63;
  const int wv = tid >> 6;
  const int lr = lane & 15;
  const int lg = lane >> 4;
  const int koff = lg * 8;

  const int xcd = blockIdx.x & 7;
  const int j_  = blockIdx.x >> 3;
  const int img  = xcd * 8 + (j_ & 7);
  const int cap0 = (j_ >> 3) * 2;
  const int pid0 = img * NCAP + cap0;

  const float* qryp[2];
  qryp[0] = cap_emb + (size_t)cap0 * (NWORD * EMBED);
  qryp[1] = cap_emb + (size_t)(cap0 + 1) * (NWORD * EMBED);
  const u16t* imgW  = ws + WS_IMG + (size_t)img * (NREG * EMBED);
  const u16t* ctxTW = ws + WS_CTXT + (size_t)img * (EMBED * 64);
  const u16t* alvW = ws + WS_ALV + (size_t)m * (SIMDIM * EMBED);
  const u16t* kwW  = ws + WS_KW  + (size_t)m * (SIMDIM * SIMDIM);
  const u16t* sw1W = ws + WS_SW1 + (size_t)m * (HSD * SIMDIM);

  if (tid < 40) {
    int p = tid / 20, q = tid % 20;
    smoothq[p][q] = (m == 0) ? 9.0f : smooth_g[(size_t)(pid0 + p) * 20 + q];
  }
  if (m > 0 && tid < 512) {
    int p = tid >> 8, t = tid & 255;
    sim_hig[p][t] = shig_g[(size_t)(pid0 + p) * 256 + t];
  }
  __syncthreads();

  // ---- A ----
#pragma unroll
  for (int p = 0; p < 2; ++p) {
    const float* qr = qryp[p];
    if (m == 0) {
#pragma unroll 4
      for (int q = 0; q < NWORD; ++q)
        qsrep[p][q * QSTR + tid] = f2bf(qr[q * 1024 + tid]);
    } else {
      const signed char* mg = mat_g + (size_t)(pid0 + p) * 20480;
#pragma unroll 4
      for (int q = 0; q < NWORD; ++q) {
        float mv = (float)mg[q * 1024 + tid] * (1.f / 127.f);
        qsrep[p][q * QSTR + tid] = f2bf(qr[q * 1024 + tid] * mv);
      }
    }
  }
  __syncthreads();

  // ---- B ----
  if (wv < 12) {
    int p = wv / 6, sub = wv % 6;
    int q0 = (sub & 1) * 16, s0 = (sub >> 1) * 16;
    int ari = q0 + lr; bool am = ari >= NWORD; int ar = am ? 0 : ari;
    int bri = s0 + lr; bool bm = bri >= NREG;  int br = bm ? 0 : bri;
    const u16t* ap = qsrep[p] + ar * QSTR + koff;
    const u16t* bp = imgW + (size_t)br * 1024 + koff;
    f4 acc0 = {0.f,0.f,0.f,0.f}, acc1 = {0.f,0.f,0.f,0.f};
#pragma unroll 2
    for (int kk = 0; kk < 32; kk += 2) {
      bf8 a0 = *(const bf8*)(ap + kk * 32);       if (am) a0 = zero8();
      bf8 b0 = *(const bf8*)(bp + kk * 32);       if (bm) b0 = zero8();
      bf8 a1 = *(const bf8*)(ap + (kk + 1) * 32); if (am) a1 = zero8();
      bf8 b1 = *(const bf8*)(bp + (kk + 1) * 32); if (bm) b1 = zero8();
      acc0 = MFMA16(a0, b0, acc0);
      acc1 = MFMA16(a1, b1, acc1);
    }
    f4 acc = acc0 + acc1;
#pragma unroll
    for (int r = 0; r < 4; ++r) {
      int q = q0 + lg * 4 + r, s = s0 + lr;
      if (q < NWORD && s < NREG) {
        float x = acc[r];
        attnT[p][q * ATSTR + s] = (x > 0.f) ? x : 0.1f * x;
      }
    }
  }
  __syncthreads();

  // ---- C ----
  if (tid < 72) {
    int p = tid / 36, s = tid % 36;
    float ss = 0.f;
#pragma unroll
    for (int q = 0; q < NWORD; ++q) { float v = attnT[p][q * ATSTR + s]; ss += v * v; }
    colscale[p][s] = 1.f / (sqrtf(ss) + EPS);
  }
  __syncthreads();

  // ---- D ----
#pragma unroll
  for (int pass = 0; pass < 3; ++pass) {
    int task = wv + pass * 16;
    if (task < 40) {
      int p = task / 20, q = task % 20;
      float x = (lane < NREG)
              ? attnT[p][q * ATSTR + lane] * colscale[p][lane] * smoothq[p][q] : -1e30f;
      float mx = wmax(x);
      float e = (lane < NREG) ? __expf(x - mx) : 0.f;
      float s = wsum(e);
      p_bf[p][q * PSTR + lane] = f2bf(e / s);
    }
  }
  __syncthreads();

  // ---- E ----
  {
    float s2[2][8];
#pragma unroll
    for (int p = 0; p < 2; ++p)
#pragma unroll
      for (int i = 0; i < 8; ++i) s2[p][i] = 0.f;
#pragma unroll
    for (int nt = 0; nt < 4; ++nt) {
      int d0 = wv * 64 + nt * 16;
      const u16t* bp = ctxTW + (size_t)(d0 + lr) * 64 + koff;
      bf8 b0 = *(const bf8*)(bp);
      bf8 b1 = *(const bf8*)(bp + 32);
      int d = d0 + lr;
#pragma unroll
      for (int p = 0; p < 2; ++p)
#pragma unroll
        for (int m2 = 0; m2 < 2; ++m2) {
          int row = m2 * 16 + lr;
          bf8 pa0, pa1;
          if (m2 == 0 || row < NWORD) {
            pa0 = *(const bf8*)(p_bf[p] + row * PSTR + koff);
            pa1 = *(const bf8*)(p_bf[p] + row * PSTR + 32 + koff);
          } else { pa0 = zero8(); pa1 = zero8(); }
          f4 acc = {0.f,0.f,0.f,0.f};
          acc = MFMA16(pa0, b0, acc);
          acc = MFMA16(pa1, b1, acc);
#pragma unroll
          for (int r = 0; r < 4; ++r) {
            int q = m2 * 16 + lg * 4 + r;
            s2[p][m2 * 4 + r] += acc[r] * acc[r];
            if (q < NWORD) qsrep[p][q * QSTR + d] = f2bf(acc[r]);
          }
        }
    }
#pragma unroll
    for (int o = 1; o < 16; o <<= 1)
#pragma unroll
      for (int p = 0; p < 2; ++p)
#pragma unroll
        for (int i = 0; i < 8; ++i) s2[p][i] += __shfl_xor(s2[p][i], o);
    if (lr == 0)
#pragma unroll
      for (int p = 0; p < 2; ++p) {
#pragma unroll
        for (int r = 0; r < 4; ++r) red[p][wv * 20 + lg * 4 + r] = s2[p][r];
        if (lg == 0)
#pragma unroll
          for (int r = 0; r < 4; ++r) red[p][wv * 20 + 16 + r] = s2[p][4 + r];
      }
    __syncthreads();
    if (tid < 40) {
      int p = tid / 20, q = tid % 20;
      float s = 0.f;
#pragma unroll
      for (int w = 0; w < 16; ++w) s += red[p][w * 20 + q];
      rq[p][q] = 1.f / (sqrtf(s) + EPS);
    }
    __syncthreads();
#pragma unroll
    for (int p = 0; p < 2; ++p) {
      const float* qr = qryp[p];
#pragma unroll
      for (int nt = 0; nt < 4; ++nt) {
        int d = wv * 64 + nt * 16 + lr;
#pragma unroll
        for (int m2 = 0; m2 < 2; ++m2)
#pragma unroll
          for (int r = 0; r < 4; ++r) {
            int q = m2 * 16 + lg * 4 + r;
            if (q < NWORD) {
              float wn = bf2f(qsrep[p][q * QSTR + d]) * rq[p][q];
              float t = qr[q * 1024 + d] - wn;
              qsrep[p][q * QSTR + d] = f2bf(t * t);
            }
          }
      }
    }
  }
  __syncthreads();

  // ---- F ----
  {
    int t_ = wv * 16 + lr;
    const u16t* bp = alvW + (size_t)t_ * 1024 + koff;
    int ari = 16 + lr; bool am = ari >= NWORD; int ar = am ? 0 : ari;
    f4 a[2][2];
#pragma unroll
    for (int p = 0; p < 2; ++p) { a[p][0] = (f4){0,0,0,0}; a[p][1] = (f4){0,0,0,0}; }
#pragma unroll 2
    for (int kk = 0; kk < 32; ++kk) {
      bf8 b = *(const bf8*)(bp + kk * 32);
#pragma unroll
      for (int p = 0; p < 2; ++p) {
        bf8 x0 = *(const bf8*)(qsrep[p] + lr * QSTR + kk * 32 + koff);
        bf8 x1 = *(const bf8*)(qsrep[p] + ar * QSTR + kk * 32 + koff); if (am) x1 = zero8();
        a[p][0] = MFMA16(x0, b, a[p][0]);
        a[p][1] = MFMA16(x1, b, a[p][1]);
      }
    }
    float bias = alv_b[m * SIMDIM + t_];
    float s2[2][8];
#pragma unroll
    for (int p = 0; p < 2; ++p) {
#pragma unroll
      for (int r = 0; r < 4; ++r) { a[p][0][r] += bias; s2[p][r] = a[p][0][r] * a[p][0][r]; }
#pragma unroll
      for (int r = 0; r < 4; ++r) {
        a[p][1][r] += bias;
        s2[p][4 + r] = (lg == 0) ? a[p][1][r] * a[p][1][r] : 0.f;
      }
    }
#pragma unroll
    for (int o = 1; o < 16; o <<= 1)
#pragma unroll
      for (int p = 0; p < 2; ++p)
#pragma unroll
        for (int i = 0; i < 8; ++i) s2[p][i] += __shfl_xor(s2[p][i], o);
    if (lr == 0)
#pragma unroll
      for (int p = 0; p < 2; ++p) {
#pragma unroll
        for (int r = 0; r < 4; ++r) red[p][wv * 20 + lg * 4 + r] = s2[p][r];
        if (lg == 0)
#pragma unroll
          for (int r = 0; r < 4; ++r) red[p][wv * 20 + 16 + r] = s2[p][4 + r];
      }
    __syncthreads();
    if (tid < 40) {
      int p = tid / 20, q = tid % 20;
      float s = 0.f;
#pragma unroll
      for (int w = 0; w < 16; ++w) s += red[p][w * 20 + q];
      rq[p][q] = 1.f / (sqrtf(s) + EPS);
    }
    __syncthreads();
#pragma unroll
    for (int p = 0; p < 2; ++p) {
      u16t* sg = smid_g + (size_t)(pid0 + p) * 5120;
#pragma unroll
      for (int r = 0; r < 4; ++r) {
        int q = lg * 4 + r;
        float v = a[p][0][r] * rq[p][q];
        u16t hv = f2bf(v);
        ((float*)(qsrep[p] + q * QSTR + 512))[t_] = v;
        smidb[p][q * SMSTR + t_] = hv;
        sg[q * 256 + t_] = hv;
      }
      if (lg == 0)
#pragma unroll
        for (int r = 0; r < 4; ++r) {
          int q = 16 + r;
          float v = a[p][1][r] * rq[p][q];
          u16t hv = f2bf(v);
          ((float*)(qsrep[p] + q * QSTR + 512))[t_] = v;
          smidb[p][q * SMSTR + t_] = hv;
          sg[q * 256 + t_] = hv;
        }
    }
  }
  __syncthreads();

  // ---- G ----
  if (m == 0 && tid < 512) {
    int p = tid >> 8, t = tid & 255;
    float s = 0.f;
#pragma unroll
    for (int q = 0; q < NWORD; ++q) s += ((const float*)(qsrep[p] + q * QSTR + 512))[t];
    sim_hig[p][t] = s * (1.f / NWORD);
  }
  __syncthreads();

  // ---- hs/ss ----
  if (m < 2) {
    if (wv < 8) {
      int j0 = wv * 16;
      int ari = 16 + lr; bool am = ari >= NWORD; int ar = am ? 0 : ari;
      f4 h[2][2];
#pragma unroll
      for (int p = 0; p < 2; ++p) { h[p][0] = (f4){0,0,0,0}; h[p][1] = (f4){0,0,0,0}; }
#pragma unroll 2
      for (int kk = 0; kk < 8; ++kk) {
        bf8 b = *(const bf8*)(sw1W + (size_t)(j0 + lr) * 256 + kk * 32 + koff);
#pragma unroll
        for (int p = 0; p < 2; ++p) {
          bf8 x0 = *(const bf8*)(smidb[p] + lr * SMSTR + kk * 32 + koff);
          bf8 x1 = *(const bf8*)(smidb[p] + ar * SMSTR + kk * 32 + koff); if (am) x1 = zero8();
          h[p][0] = MFMA16(x0, b, h[p][0]);
          h[p][1] = MFMA16(x1, b, h[p][1]);
        }
      }
      int j = j0 + lr;
      float bias = sb1[m * HSD + j];
      float s2v = sw2[m * HSD + j];
      float part[2][8];
#pragma unroll
      for (int p = 0; p < 2; ++p) {
#pragma unroll
        for (int r = 0; r < 4; ++r) part[p][r] = ftanh(h[p][0][r] + bias) * s2v;
#pragma unroll
        for (int r = 0; r < 4; ++r)
          part[p][4 + r] = (lg == 0) ? ftanh(h[p][1][r] + bias) * s2v : 0.f;
      }
#pragma unroll
      for (int o = 1; o < 16; o <<= 1)
#pragma unroll
        for (int p = 0; p < 2; ++p)
#pragma unroll
          for (int i = 0; i < 8; ++i) part[p][i] += __shfl_xor(part[p][i], o);
      if (lr == 0)
#pragma unroll
        for (int p = 0; p < 2; ++p) {
#pragma unroll
          for (int r = 0; r < 4; ++r) red[p][wv * 20 + lg * 4 + r] = part[p][r];
          if (lg == 0)
#pragma unroll
            for (int r = 0; r < 4; ++r) red[p][wv * 20 + 16 + r] = part[p][4 + r];
        }
    }
    __syncthreads();
    if (tid < 40) {
      int p = tid / 20, q = tid % 20;
      float s = 0.f;
#pragma unroll
      for (int w = 0; w < 8; ++w) s += red[p][w * 20 + q];
      float ns = fmaxf(0.f, s + sb2[m] + smoothq[p][q]);
      smooth_g[(size_t)(pid0 + p) * 20 + q] = ns;
    }
    __syncthreads();
  }

  // ---- I ----
  {
    int t_ = wv * 16 + lr;
    int ari = 16 + lr; bool am = ari >= NWORD; int ar = am ? 0 : ari;
    float hq[2];
#pragma unroll
    for (int p = 0; p < 2; ++p) {
      const float4* wq = (const float4*)(rar_qw + ((size_t)m * SIMDIM + t_) * SIMDIM);
      const float4* sh = (const float4*)sim_hig[p];
      float hacc = 0.f;
#pragma unroll 2
      for (int i = 0; i < SIMDIM / 4; ++i) hacc += d4(wq[i], sh[i]);
      hq[p] = ftanh(hacc + rar_qb[m * SIMDIM + t_]) * rar_vw[m * SIMDIM + t_];
    }
    f4 k[2][2];
#pragma unroll
    for (int p = 0; p < 2; ++p) { k[p][0] = (f4){0,0,0,0}; k[p][1] = (f4){0,0,0,0}; }
#pragma unroll 2
    for (int kk = 0; kk < 8; ++kk) {
      bf8 b = *(const bf8*)(kwW + (size_t)t_ * 256 + kk * 32 + koff);
#pragma unroll
      for (int p = 0; p < 2; ++p) {
        bf8 x0 = *(const bf8*)(smidb[p] + lr * SMSTR + kk * 32 + koff);
        bf8 x1 = *(const bf8*)(smidb[p] + ar * SMSTR + kk * 32 + koff); if (am) x1 = zero8();
        k[p][0] = MFMA16(x0, b, k[p][0]);
        k[p][1] = MFMA16(x1, b, k[p][1]);
      }
    }
    float kb = rar_kb[m * SIMDIM + t_];
    float part[2][8];
#pragma unroll
    for (int p = 0; p < 2; ++p) {
#pragma unroll
      for (int r = 0; r < 4; ++r) part[p][r] = ftanh(k[p][0][r] + kb) * hq[p];
#pragma unroll
      for (int r = 0; r < 4; ++r)
        part[p][4 + r] = (lg == 0) ? ftanh(k[p][1][r] + kb) * hq[p] : 0.f;
    }
#pragma unroll
    for (int o = 1; o < 16; o <<= 1)
#pragma unroll
      for (int p = 0; p < 2; ++p)
#pragma unroll
        for (int i = 0; i < 8; ++i) part[p][i] += __shfl_xor(part[p][i], o);
    if (lr == 0)
#pragma unroll
      for (int p = 0; p < 2; ++p) {
#pragma unroll
        for (int r = 0; r < 4; ++r) red[p][wv * 20 + lg * 4 + r] = part[p][r];
        if (lg == 0)
#pragma unroll
          for (int r = 0; r < 4; ++r) red[p][wv * 20 + 16 + r] = part[p][4 + r];
      }
  }
  __syncthreads();
  if (tid < 40) {
    int p = tid / 20, q = tid % 20;
    float s = 0.f;
#pragma unroll
    for (int w = 0; w < 16; ++w) s += red[p][w * 20 + q];
    logits[p][q] = s + rar_vb[m];
  }
  __syncthreads();
  if (tid < 128) {
    int p = tid >> 6;
    float v = (lane < NWORD) ? logits[p][lane] : -1e30f;
    float mx = wmax(v);
    float e = (lane < NWORD) ? __expf(v - mx) : 0.f;
    float s = wsum(e);
    if (lane < NWORD) wsm[p][lane] = e / s;
  }
  __syncthreads();
  if (tid < 512) {
    int p = tid >> 8, t = tid & 255;
    float a = 0.f;
#pragma unroll
    for (int q = 0; q < NWORD; ++q) a += wsm[p][q] * ((const float*)(qsrep[p] + q * QSTR + 512))[t];
    sim_hig[p][t] = a;
  }
  __syncthreads();
  if (tid < 128) {
    int p = tid >> 6;
    float4 v = ((const float4*)sim_hig[p])[lane];
    float s = wsum(d4(v, v));
    if (lane == 0) ssig_s[p] = 1.f / (sqrtf(s) + EPS);
  }
  __syncthreads();

  if (m < 2) {
    if (tid < 512) {
      int p = tid >> 8, t = tid & 255;
      shig_g[(size_t)(pid0 + p) * 256 + t] = sim_hig[p][t] * ssig_s[p];
    }
  } else {
    if (tid < 128) {
      int p = tid >> 6;
      float4 s4v = ((const float4*)sim_hig[p])[lane];
      float4 w4v = ((const float4*)eval_w)[lane];
      float v = wsum(d4(s4v, w4v)) * ssig_s[p];
      if (lane == 0)
        out[pid0 + p] = 1.f / (1.f + __expf(-(v + eval_b[0])));
    }
  }
}

// =================== K2: batched hm+mm GEMM + matrix update ===================
// One block = 4 pairs (M=80). 16 waves, launch_bounds(1024,4) => 128 regs (no spills).
// nt-outer tiling: only acc[5] (20 regs) live per tile. mat writes staged in LDS,
// then one coalesced int4 RMW pass. LDS = 81920 (hm) + 81920 (mat) = 163840 (full CU).
__global__ __launch_bounds__(1024, 4) void simenc_k2(
    const float* __restrict__ mb1, const float* __restrict__ mb2,
    const u16t* __restrict__ ws,
    const u16t* __restrict__ smid_g, signed char* __restrict__ mat_g,
    int m)
{
  __shared__ __attribute__((aligned(16))) u16t hm_l[80 * 512];        // 81920B, XOR-swizzled
  __shared__ __attribute__((aligned(16))) signed char mat_l[80 * 1024]; // 81920B

  const int tid = threadIdx.x;
  const int lane = tid & 63;
  const int wv = tid >> 6;      // 0..15
  const int lr = lane & 15;
  const int lg = lane >> 4;
  const int koff = lg * 8;

  const int pid0 = blockIdx.x * 4;
  const u16t* mw1W = ws + WS_MW1 + (size_t)m * (H1 * SIMDIM);
  const u16t* mw2W = ws + WS_MW2 + (size_t)m * (EMBED * H1);
  const u16t* smidB = smid_g + (size_t)pid0 * 5120;   // 80 contiguous rows of 256

  // ---- phase 1: hm = tanh(smid . mw1^T + mb1); nt-outer, acc[5] live ----
#pragma unroll
  for (int nt = 0; nt < 2; ++nt) {
    int j0 = (wv * 2 + nt) * 16;
    f4 acc[5];
#pragma unroll
    for (int mt = 0; mt < 5; ++mt) acc[mt] = (f4){0,0,0,0};
#pragma unroll 2
    for (int kk = 0; kk < 8; ++kk) {
      bf8 b = *(const bf8*)(mw1W + (size_t)(j0 + lr) * 256 + kk * 32 + koff);
#pragma unroll
      for (int mt = 0; mt < 5; ++mt) {
        bf8 a = *(const bf8*)(smidB + (size_t)(mt * 16 + lr) * 256 + kk * 32 + koff);
        acc[mt] = MFMA16(a, b, acc[mt]);
      }
    }
    int j = j0 + lr;
    float bias = mb1[m * H1 + j];
#pragma unroll
    for (int mt = 0; mt < 5; ++mt)
#pragma unroll
      for (int r = 0; r < 4; ++r) {
        int rb = mt * 16 + lg * 4 + r;
        unsigned byteoff = (unsigned)rb * 1024u
                         + (((unsigned)j * 2u) ^ (((unsigned)rb & 7u) << 4));
        *(u16t*)((char*)hm_l + byteoff) = f2bf(ftanh(acc[mt][r] + bias));
      }
  }
  __syncthreads();

  // ---- phase 2: mm = hm . mw2^T + mb2; v = tanh(mm) staged int8 in mat_l ----
#pragma unroll
  for (int nt = 0; nt < 4; ++nt) {
    int d0 = (wv * 4 + nt) * 16;
    f4 acc[5];
#pragma unroll
    for (int mt = 0; mt < 5; ++mt) acc[mt] = (f4){0,0,0,0};
#pragma unroll 2
    for (int kk = 0; kk < 16; ++kk) {
      bf8 b = *(const bf8*)(mw2W + (size_t)(d0 + lr) * 512 + kk * 32 + koff);
#pragma unroll
      for (int mt = 0; mt < 5; ++mt) {
        int rb = mt * 16 + lr;
        unsigned byteoff = (unsigned)rb * 1024u
                         + (((unsigned)(kk * 64 + lg * 16)) ^ (((unsigned)rb & 7u) << 4));
        bf8 a = *(const bf8*)((const char*)hm_l + byteoff);
        acc[mt] = MFMA16(a, b, acc[mt]);
      }
    }
    int d = d0 + lr;
    float bias = mb2[m * EMBED + d];
#pragma unroll
    for (int mt = 0; mt < 5; ++mt)
#pragma unroll
      for (int r = 0; r < 4; ++r) {
        int rb = mt * 16 + lg * 4 + r;
        float v = ftanh(acc[mt][r] + bias);
        mat_l[rb * 1024 + d] = (signed char)__float2int_rn(v * 127.f);
      }
  }
  __syncthreads();

  // ---- phase 3: coalesced RMW of mat_g (int4 granularity) ----
  {
    signed char* matB = mat_g + (size_t)pid0 * 20480;   // 80KB contiguous
#pragma unroll
    for (int i = 0; i < 5; ++i) {
      int off = i * 16384 + tid * 16;
      int4 sv = *(const int4*)(mat_l + off);
      int4 ov;
      if (m > 0) ov = *(const int4*)(matB + off);
      const signed char* svb = (const signed char*)&sv;
      const signed char* ovb = (const signed char*)&ov;
      int4 res;
      signed char* rsb = (signed char*)&res;
#pragma unroll
      for (int b = 0; b < 16; ++b) {
        float v = (float)svb[b] * (1.f / 127.f);
        float mo = (m == 0) ? 1.f : (float)ovb[b] * (1.f / 127.f);
        float mn = fminf(fmaxf(v + mo, -1.f), 1.f);
        rsb[b] = (signed char)__float2int_rn(mn * 127.f);
      }
      *(int4*)(matB + off) = res;
    }
  }
}

// ---------------- fallback: f32 VALU kernel (no usable ws) ----------------
__global__ __launch_bounds__(1024) void simenc_valu(
    const float* __restrict__ img_emb, const float* __restrict__ cap_emb,
    const float* __restrict__ alv_w,  const float* __restrict__ alv_b,
    const float* __restrict__ rar_qw, const float* __restrict__ rar_qb,
    const float* __restrict__ rar_kw, const float* __restrict__ rar_kb,
    const float* __restrict__ rar_vw, const float* __restrict__ rar_vb,
    const float* __restrict__ sw1, const float* __restrict__ sb1,
    const float* __restrict__ sw2, const float* __restrict__ sb2,
    const float* __restrict__ mw1, const float* __restrict__ mb1,
    const float* __restrict__ mw2, const float* __restrict__ mb2,
    const float* __restrict__ eval_w, const float* __restrict__ eval_b,
    float* __restrict__ out)
{
  __shared__ float buf[NWORD * EMBED];
  __shared__ float smid[NWORD * SIMDIM];
  __shared__ float attn_raw[NREG * NWORD];
  __shared__ float attnT[NWORD * NREG];
  __shared__ float smoothq[NWORD];
  __shared__ float sim_hig[SIMDIM];
  __shared__ float hqu[SIMDIM];
  __shared__ float wsm_[NWORD];
  __shared__ float red[16 * NWORD];
  __shared__ float rq[NWORD];
  __shared__ float ssig;

  const int tid = threadIdx.x;
  const int lane = tid & 63;
  const int wv = tid >> 6;
  const int pair = blockIdx.x;
  const int img = pair & 63;
  const int cap = pair >> 6;
  const float* ctx = img_emb + (size_t)img * (NREG * EMBED);
  const float* qry = cap_emb + (size_t)cap * (NWORD * EMBED);

  float mat[NWORD];
#pragma unroll
  for (int q = 0; q < NWORD; ++q) mat[q] = 1.f;
  if (tid < NWORD) smoothq[tid] = 9.f;
  __syncthreads();

  for (int m = 0; m < 3; ++m) {
#pragma unroll 4
    for (int q = 0; q < NWORD; ++q)
      buf[q * EMBED + tid] = qry[q * EMBED + tid] * mat[q];
    __syncthreads();
    if (tid < NWORD * NREG) {
      int q = tid / NREG, s = tid % NREG;
      const float4* c4 = (const float4*)(ctx + s * EMBED);
      const float4* q4 = (const float4*)(buf + q * EMBED);
      float acc = 0.f;
#pragma unroll 4
      for (int i = 0; i < EMBED / 4; ++i) acc += d4(c4[i], q4[i]);
      attn_raw[s * NWORD + q] = (acc > 0.f) ? acc : 0.1f * acc;
    }
    __syncthreads();
    if (tid < NREG) {
      int s = tid; float sumsq = 0.f;
#pragma unroll
      for (int q = 0; q < NWORD; ++q) { float v = attn_raw[s * NWORD + q]; sumsq += v * v; }
      float sc = 1.f / (sqrtf(sumsq) + EPS);
#pragma unroll
      for (int q = 0; q < NWORD; ++q) attnT[q * NREG + s] = attn_raw[s * NWORD + q] * sc;
    }
    __syncthreads();
    if (tid < NWORD) {
      int q = tid; float sm = smoothq[q]; float mx = -1e30f;
      for (int s = 0; s < NREG; ++s) mx = fmaxf(mx, attnT[q * NREG + s] * sm);
      float sum = 0.f;
      for (int s = 0; s < NREG; ++s) { float e = __expf(attnT[q * NREG + s] * sm - mx); attnT[q * NREG + s] = e; sum += e; }
      float r = 1.f / sum;
      for (int s = 0; s < NREG; ++s) attnT[q * NREG + s] *= r;
    }
    __syncthreads();
    {
      float wacc[NWORD];
#pragma unroll
      for (int q = 0; q < NWORD; ++q) wacc[q] = 0.f;
#pragma unroll
      for (int sc_ = 0; sc_ < 3; ++sc_) {
        float c[12];
#pragma unroll
        for (int i = 0; i < 12; ++i) c[i] = ctx[(sc_ * 12 + i) * EMBED + tid];
#pragma unroll
        for (int q = 0; q < NWORD; ++q) {
          const float4* a4 = (const float4*)(attnT + q * NREG + sc_ * 12);
          float4 a0 = a4[0], a1 = a4[1], a2 = a4[2];
          wacc[q] += a0.x*c[0] + a0.y*c[1] + a0.z*c[2] + a0.w*c[3]
                   + a1.x*c[4] + a1.y*c[5] + a1.z*c[6] + a1.w*c[7]
                   + a2.x*c[8] + a2.y*c[9] + a2.z*c[10] + a2.w*c[11];
        }
      }
#pragma unroll
      for (int q = 0; q < NWORD; ++q) {
        float v = wsum(wacc[q] * wacc[q]);
        if (lane == 0) red[wv * NWORD + q] = v;
      }
      __syncthreads();
      if (tid < NWORD) {
        float s = 0.f;
#pragma unroll
        for (int w = 0; w < 16; ++w) s += red[w * NWORD + tid];
        rq[tid] = 1.f / (sqrtf(s) + EPS);
      }
      __syncthreads();
#pragma unroll 4
      for (int q = 0; q < NWORD; ++q) {
        float wn = wacc[q] * rq[q];
        float t = qry[q * EMBED + tid] - wn;
        buf[q * EMBED + tid] = t * t;
      }
    }
    __syncthreads();
    {
      int t = tid & 255, g = tid >> 8;
      const float4* w4 = (const float4*)(alv_w + ((size_t)m * SIMDIM + t) * EMBED);
      float acc[5] = {0, 0, 0, 0, 0};
      for (int i = 0; i < EMBED / 4; ++i) {
        float4 w = w4[i];
#pragma unroll
        for (int k = 0; k < 5; ++k) acc[k] += d4(w, ((const float4*)(buf + (g + 4 * k) * EMBED))[i]);
      }
      float b = alv_b[m * SIMDIM + t];
#pragma unroll
      for (int k = 0; k < 5; ++k) smid[(g + 4 * k) * SIMDIM + t] = acc[k] + b;
    }
    __syncthreads();
#pragma unroll
    for (int rep = 0; rep < 2; ++rep) {
      int q = wv + rep * 16;
      if (q < NWORD) {
        float4 v = ((const float4*)(smid + q * SIMDIM))[lane];
        float s = wsum(d4(v, v));
        if (lane == 0) rq[q] = 1.f / (sqrtf(s) + EPS);
      }
    }
    __syncthreads();
#pragma unroll
    for (int k = 0; k < 5; ++k) { int e = tid + k * 1024; smid[e] *= rq[e >> 8]; }
    __syncthreads();
    if (m == 0 && tid < SIMDIM) {
      float s = 0.f;
#pragma unroll
      for (int q = 0; q < NWORD; ++q) s += smid[q * SIMDIM + tid];
      sim_hig[tid] = s * (1.f / NWORD);
    }
    __syncthreads();
    if (m < 2) {
      {
        int j = tid & 511, g = tid >> 9;
        const float4* w4 = (const float4*)(mw1 + ((size_t)m * H1 + j) * SIMDIM);
        float acc[10];
#pragma unroll
        for (int k = 0; k < 10; ++k) acc[k] = 0.f;
        for (int i = 0; i < SIMDIM / 4; ++i) {
          float4 w = w4[i];
#pragma unroll
          for (int k = 0; k < 10; ++k) acc[k] += d4(w, ((const float4*)(smid + (g + 2 * k) * SIMDIM))[i]);
        }
        float b = mb1[m * H1 + j];
#pragma unroll
        for (int k = 0; k < 10; ++k) buf[(g + 2 * k) * H1 + j] = ftanh(acc[k] + b);
      }
      __syncthreads();
      {
        const float4* w4 = (const float4*)(mw2 + ((size_t)m * EMBED + tid) * H1);
        float acc[NWORD];
#pragma unroll
        for (int q = 0; q < NWORD; ++q) acc[q] = 0.f;
        for (int i = 0; i < H1 / 4; ++i) {
          float4 w = w4[i];
#pragma unroll
          for (int q = 0; q < NWORD; ++q) acc[q] += d4(w, ((const float4*)(buf + q * H1))[i]);
        }
        float b = mb2[m * EMBED + tid];
#pragma unroll
        for (int q = 0; q < NWORD; ++q)
          mat[q] = fminf(fmaxf(ftanh(acc[q] + b) + mat[q], -1.f), 1.f);
      }
      {
        int j = tid & 127, g = tid >> 7;
        const float4* w4 = (const float4*)(sw1 + ((size_t)m * HSD + j) * SIMDIM);
        float a0 = 0.f, a1 = 0.f, a2 = 0.f;
        for (int i = 0; i < SIMDIM / 4; ++i) {
          float4 w = w4[i];
          a0 += d4(w, ((const float4*)(smid + g * SIMDIM))[i]);
          a1 += d4(w, ((const float4*)(smid + (g + 8) * SIMDIM))[i]);
          if (g < 4) a2 += d4(w, ((const float4*)(smid + (g + 16) * SIMDIM))[i]);
        }
        float b = sb1[m * HSD + j];
        buf[10240 + g * HSD + j] = ftanh(a0 + b);
        buf[10240 + (g + 8) * HSD + j] = ftanh(a1 + b);
        if (g < 4) buf[10240 + (g + 16) * HSD + j] = ftanh(a2 + b);
      }
      __syncthreads();
      {
        const float* sw2m = sw2 + m * HSD;
#pragma unroll
        for (int rep = 0; rep < 2; ++rep) {
          int q = wv + rep * 16;
          if (q < NWORD) {
            float v = buf[10240 + q * HSD + lane] * sw2m[lane]
                    + buf[10240 + q * HSD + 64 + lane] * sw2m[64 + lane];
            v = wsum(v);
            if (lane == 0) smoothq[q] = fmaxf(0.f, v + sb2[m] + smoothq[q]);
          }
        }
      }
      __syncthreads();
    }
    {
      int t = tid & 255, g = tid >> 8;
      const float4* w4 = (const float4*)(rar_kw + ((size_t)m * SIMDIM + t) * SIMDIM);
      float acc[5] = {0, 0, 0, 0, 0};
      for (int i = 0; i < SIMDIM / 4; ++i) {
        float4 w = w4[i];
#pragma unroll
        for (int k = 0; k < 5; ++k) acc[k] += d4(w, ((const float4*)(smid + (g + 4 * k) * SIMDIM))[i]);
      }
      float b = rar_kb[m * SIMDIM + t];
#pragma unroll
      for (int k = 0; k < 5; ++k) buf[12800 + (g + 4 * k) * SIMDIM + t] = ftanh(acc[k] + b);
    }
    if (tid < SIMDIM) {
      const float4* w4 = (const float4*)(rar_qw + ((size_t)m * SIMDIM + tid) * SIMDIM);
      const float4* s4 = (const float4*)sim_hig;
      float acc = 0.f;
      for (int i = 0; i < SIMDIM / 4; ++i) acc += d4(w4[i], s4[i]);
      hqu[tid] = ftanh(acc + rar_qb[m * SIMDIM + tid]) * rar_vw[m * SIMDIM + tid];
    }
    __syncthreads();
#pragma unroll
    for (int rep = 0; rep < 2; ++rep) {
      int q = wv + rep * 16;
      if (q < NWORD) {
        float4 a = ((const float4*)(buf + 12800 + q * SIMDIM))[lane];
        float4 u = ((const float4*)hqu)[lane];
        float v = wsum(d4(a, u));
        if (lane == 0) red[q] = v + rar_vb[m];
      }
    }
    __syncthreads();
    if (tid < 64) {
      float v = (tid < NWORD) ? red[tid] : -1e30f;
      float mx = wmax(v);
      float e = (tid < NWORD) ? __expf(v - mx) : 0.f;
      float s = wsum(e);
      if (tid < NWORD) wsm_[tid] = e / s;
    }
    __syncthreads();
    if (tid < SIMDIM) {
      float acc = 0.f;
#pragma unroll
      for (int q = 0; q < NWORD; ++q) acc += wsm_[q] * smid[q * SIMDIM + tid];
      sim_hig[tid] = acc;
    }
    __syncthreads();
    if (tid < 64) {
      float4 v = ((const float4*)sim_hig)[tid];
      float s = wsum(d4(v, v));
      if (tid == 0) ssig = 1.f / (sqrtf(s) + EPS);
    }
    __syncthreads();
    if (tid < SIMDIM) sim_hig[tid] *= ssig;
    __syncthreads();
  }
  if (tid < 64) {
    float4 s4v = ((const float4*)sim_hig)[tid];
    float4 w4v = ((const float4*)eval_w)[tid];
    float v = wsum(d4(s4v, w4v));
    if (tid == 0) out[img * NCAP + cap] = 1.f / (1.f + __expf(-(v + eval_b[0])));
  }
}

extern "C" void kernel_launch(void* const* d_in, const int* in_sizes, int n_in,
                              void* d_out, int out_size, void* d_ws, size_t ws_size,
                              hipStream_t stream) {
  (void)in_sizes; (void)n_in; (void)out_size;
  u16t* ws = (u16t*)d_ws;

  if (ws_size >= (size_t)WS_FULL_BYTES) {
    cvt_kernel<<<2048, 1024, 0, stream>>>(
        (const float*)d_in[3],  (const float*)d_in[7],  (const float*)d_in[15],
        (const float*)d_in[17], (const float*)d_in[11], (const float*)d_in[0], ws);
    ctxt_kernel<<<1024, 256, 0, stream>>>((const float*)d_in[0], ws + WS_CTXT);

    signed char* mat_g = (signed char*)d_ws + OFFB_MAT;
    u16t*  smid_g   = (u16t*)((char*)d_ws + OFFB_SMID);
    float* shig_g   = (float*)((char*)d_ws + OFFB_SHIG);
    float* smooth_g = (float*)((char*)d_ws + OFFB_SMOOTH);

    for (int m = 0; m < 3; ++m) {
      simenc_k1<<<NIMG * NCAP / 2, 1024, 0, stream>>>(
          (const float*)d_in[1],  (const float*)d_in[4],
          (const float*)d_in[5],  (const float*)d_in[6],  (const float*)d_in[8],
          (const float*)d_in[9],  (const float*)d_in[10],
          (const float*)d_in[12], (const float*)d_in[13], (const float*)d_in[14],
          (const float*)d_in[19], (const float*)d_in[20],
          ws, mat_g, smid_g, shig_g, smooth_g, m, (float*)d_out);
      if (m < 2)
        simenc_k2<<<NIMG * NCAP / 4, 1024, 0, stream>>>(
            (const float*)d_in[16], (const float*)d_in[18],
            ws, smid_g, mat_g, m);
    }
  } else {
    simenc_valu<<<NIMG * NCAP, 1024, 0, stream>>>(
        (const float*)d_in[0],  (const float*)d_in[1],
        (const float*)d_in[3],  (const float*)d_in[4],
        (const float*)d_in[5],  (const float*)d_in[6],
        (const float*)d_in[7],  (const float*)d_in[8],
        (const float*)d_in[9],  (const float*)d_in[10],
        (const float*)d_in[11], (const float*)d_in[12],
        (const float*)d_in[13], (const float*)d_in[14],
        (const float*)d_in[15], (const float*)d_in[16],
        (const float*)d_in[17], (const float*)d_in[18],
        (const float*)d_in[19], (const float*)d_in[20],
        (float*)d_out);
  }
}